// Round 5
// baseline (2855.034 us; speedup 1.0000x reference)
//
#include <hip/hip_runtime.h>
#include <stdint.h>

#define B_ 4
#define S_ 2048
#define D_ 1024
#define H_ 16
#define A_ 64
#define LN_EPS 1e-3f
#define L2E 1.4426950408889634f
#define LDK 40
#define QB 64
#define KB 128

typedef __bf16 bf16x8 __attribute__((ext_vector_type(8)));
typedef float f32x4 __attribute__((ext_vector_type(4)));

__device__ __forceinline__ f32x4 mfma16(bf16x8 a, bf16x8 b, f32x4 c) {
    return __builtin_amdgcn_mfma_f32_16x16x32_bf16(a, b, c, 0, 0, 0);
}
__device__ __forceinline__ void glds16(const void* g, void* l) {
    __builtin_amdgcn_global_load_lds(
        (const __attribute__((address_space(1))) void*)g,
        (__attribute__((address_space(3))) void*)l, 16, 0, 0);
}

// ---- 8-phase 256x256 GEMM core helpers (headsum) ----
#define SWZ(slot, r) ((slot) ^ (((r) & 1) << 2) ^ (((r) >> 1) & 3))
__device__ __forceinline__ void stage_half(const __bf16* __restrict__ src, size_t ld,
                                           __bf16* lhalf, int w, int lane) {
    #pragma unroll
    for (int i = 0; i < 2; ++i) {
        int ch = w * 2 + i;
        int r = ch * 8 + (lane >> 3);
        int sl = SWZ(lane & 7, r);
        glds16(src + (size_t)r * ld + sl * 8, lhalf + ch * 512);
    }
}
__device__ __forceinline__ bf16x8 fragS(const __bf16* h, int r, int ks, int fg) {
    return *(const bf16x8*)(h + r * 64 + SWZ(ks * 4 + fg, r) * 8);
}

// ---------------- tiled transpose + f32->bf16 convert ----------------
__global__ void k_tr_cvt(const float* __restrict__ in, __bf16* __restrict__ out,
                         int R, int C) {
    __shared__ float tile[32][33];
    size_t gbase = (size_t)blockIdx.z * R * C;
    int r0 = blockIdx.y * 32, c0 = blockIdx.x * 32;
    #pragma unroll
    for (int i = threadIdx.y; i < 32; i += 8)
        tile[i][threadIdx.x] = in[gbase + (size_t)(r0 + i) * C + c0 + threadIdx.x];
    __syncthreads();
    #pragma unroll
    for (int i = threadIdx.y; i < 32; i += 8)
        out[gbase + (size_t)(c0 + i) * R + r0 + threadIdx.x] = (__bf16)tile[threadIdx.x][i];
}

// ---------------- proj staging helpers ----------------
__device__ __forceinline__ void stage128_bf16(__bf16* dst, const __bf16* src, int ld, int t) {
    #pragma unroll
    for (int i = 0; i < 2; ++i) {
        int id = t + i * 256;
        int row = id >> 2, ch = (id & 3) * 8;
        *(uint4*)(dst + row * LDK + ch) = *(const uint4*)(src + (size_t)row * ld + ch);
    }
}
__device__ __forceinline__ void stage128_f32(__bf16* dst, const float* src, int ld, int t) {
    #pragma unroll
    for (int i = 0; i < 2; ++i) {
        int id = t + i * 256;
        int row = id >> 2, ch = (id & 3) * 8;
        const float* p = src + (size_t)row * ld + ch;
        float4 f0 = *(const float4*)p;
        float4 f1 = *(const float4*)(p + 4);
        __bf16 v8[8] = {(__bf16)f0.x, (__bf16)f0.y, (__bf16)f0.z, (__bf16)f0.w,
                        (__bf16)f1.x, (__bf16)f1.y, (__bf16)f1.z, (__bf16)f1.w};
        *(uint4*)(dst + row * LDK + ch) = *(const uint4*)v8;
    }
}
template <int NI, int NJ>
__device__ __forceinline__ void mfma_tile(const __bf16* As, const __bf16* Bs,
                                          int wm, int wn, int fr, int fg,
                                          f32x4 (&acc)[NI][NJ]) {
    bf16x8 af[NI], bv[NJ];
    #pragma unroll
    for (int i = 0; i < NI; ++i)
        af[i] = *(const bf16x8*)(As + (wm + i * 16 + fr) * LDK + fg * 8);
    #pragma unroll
    for (int j = 0; j < NJ; ++j)
        bv[j] = *(const bf16x8*)(Bs + (wn + j * 16 + fr) * LDK + fg * 8);
    #pragma unroll
    for (int i = 0; i < NI; ++i)
        #pragma unroll
        for (int j = 0; j < NJ; ++j)
            acc[i][j] = mfma16(af[i], bv[j], acc[i][j]);
}

// ---------------- Q/K projection (f32 A x bf16 W^T), 128^2 tile ----------------
__global__ __launch_bounds__(256) void k_proj_gemm(
    const float* __restrict__ Af, const __bf16* __restrict__ Bt,
    const float* __restrict__ bias, float scale, __bf16* __restrict__ out) {
    __shared__ __bf16 As[128 * LDK];
    __shared__ __bf16 Bs[128 * LDK];
    int m0 = blockIdx.y * 128, n0 = blockIdx.x * 128;
    int t = threadIdx.x, lane = t & 63, w = t >> 6;
    int wm = (w >> 1) * 64, wn = (w & 1) * 64;
    int fr = lane & 15, fg = lane >> 4;
    f32x4 acc[4][4] = {};
    for (int k0 = 0; k0 < D_; k0 += 32) {
        __syncthreads();
        stage128_f32(As, Af + (size_t)m0 * D_ + k0, D_, t);
        stage128_bf16(Bs, Bt + (size_t)n0 * D_ + k0, D_, t);
        __syncthreads();
        mfma_tile<4, 4>(As, Bs, wm, wn, fr, fg, acc);
    }
    #pragma unroll
    for (int j = 0; j < 4; ++j) {
        int n = n0 + wn + j * 16 + fr;
        float bv = bias[n];
        #pragma unroll
        for (int i = 0; i < 4; ++i)
            #pragma unroll
            for (int jj = 0; jj < 4; ++jj) {
                int m = m0 + wm + i * 16 + fg * 4 + jj;
                out[(size_t)m * (H_ * A_) + n] = (__bf16)((acc[i][j][jj] + bv) * scale);
            }
    }
}

// ---------------- fused attention: QK^T -> exp -> PV, per (q-tile, head) ----------------
// Q-tile 64 rows; K-tiles of 128; V fragments from global (L2-resident kvt).
__global__ __launch_bounds__(512, 2) void k_attn(
    const __bf16* __restrict__ qpb, const __bf16* __restrict__ kpb,
    const __bf16* __restrict__ kvtb, __bf16* __restrict__ att, int hb0) {
    __shared__ __bf16 Ks[2][KB * 64];   // [t][a], source-swizzled (slot^(r&7))
    __shared__ __bf16 Ps[QB * KB];      // [s][t], swizzled; also Q staging area
    __shared__ float lpar[QB][4];
    __shared__ float linv[QB];
    int xo = blockIdx.x;
    int qt = (xo & 1) ? (xo >> 1) : (31 - (xo >> 1));  // long blocks first
    int hl = blockIdx.y;
    int h = hb0 + hl;
    int t = threadIdx.x, lane = t & 63, w = t >> 6;
    int fr = lane & 15, fg = lane >> 4;
    int sm2 = w >> 2, sn = w & 3;

    auto stgK = [&](int kt2, int buf) {
        #pragma unroll
        for (int i = 0; i < 2; ++i) {
            int ch = w * 2 + i;
            int r = ch * 8 + (lane >> 3);
            int sl = (lane & 7) ^ (r & 7);
            glds16(kpb + (size_t)(kt2 * KB + r) * (H_ * A_) + h * A_ + sl * 8,
                   &Ks[buf][ch * 512]);
        }
    };

    // prologue: stage Q (into Ps area) + K tile 0
    {
        int r = w * 8 + (lane >> 3);
        glds16(qpb + (size_t)(qt * QB + r) * (H_ * A_) + h * A_ + (lane & 7) * 8,
               Ps + w * 512);
    }
    stgK(0, 0);
    asm volatile("s_waitcnt vmcnt(0)" ::: "memory");
    __syncthreads();
    bf16x8 qf[2][2];
    #pragma unroll
    for (int mi2 = 0; mi2 < 2; ++mi2)
        #pragma unroll
        for (int ks = 0; ks < 2; ++ks) {
            int r = (sm2 * 2 + mi2) * 16 + fr;
            qf[mi2][ks] = *(const bf16x8*)(Ps + r * 64 + ks * 32 + fg * 8);
        }
    __syncthreads();  // Q reads done before P~ writes

    f32x4 acc[4][8] = {};
    float lsum[2][4] = {};
    const int NT = (qt >> 1) + 1;
    int cur = 0;
    for (int tt = 0; tt < NT; ++tt) {
        if (tt + 1 < NT) stgK(tt + 1, cur ^ 1);
        // S = Q K^T for this wave's 2x2 sub-tiles
        f32x4 sac[2][2] = {};
        #pragma unroll
        for (int ks = 0; ks < 2; ++ks)
            #pragma unroll
            for (int mi2 = 0; mi2 < 2; ++mi2)
                #pragma unroll
                for (int nj2 = 0; nj2 < 2; ++nj2) {
                    int nr = (sn * 2 + nj2) * 16 + fr;
                    bf16x8 kf = *(const bf16x8*)(
                        &Ks[cur][nr * 64 + (((ks * 4 + fg) ^ (nr & 7)) << 3)]);
                    sac[mi2][nj2] = mfma16(qf[mi2][ks], kf, sac[mi2][nj2]);
                }
        // exp + store P~ (swizzled) + row-sum partials
        #pragma unroll
        for (int mi2 = 0; mi2 < 2; ++mi2)
            #pragma unroll
            for (int nj2 = 0; nj2 < 2; ++nj2)
                #pragma unroll
                for (int jj = 0; jj < 4; ++jj) {
                    int srow = (sm2 * 2 + mi2) * 16 + fg * 4 + jj;
                    int c = (sn * 2 + nj2) * 16 + fr;
                    int tg = tt * KB + c;
                    int sg = qt * QB + srow;
                    float p = exp2f(sac[mi2][nj2][jj] * L2E);
                    if (tg > sg) p = 0.f;
                    lsum[mi2][jj] += p;
                    Ps[srow * KB + (((c >> 3) ^ (srow & 7)) << 3) + (c & 7)] = (__bf16)p;
                }
        // barrier B: P~ visible (lgkm only; keep K-prefetch vmcnt in flight)
        asm volatile("s_waitcnt lgkmcnt(0)" ::: "memory");
        __builtin_amdgcn_s_barrier();
        __builtin_amdgcn_sched_barrier(0);
        // PV: acc += P~ x V  (V frags direct from global kvt)
        #pragma unroll
        for (int ksl = 0; ksl < 4; ++ksl) {
            int tbase = tt * KB + ksl * 32 + fg * 8;
            bf16x8 vf[8];
            #pragma unroll
            for (int nj = 0; nj < 8; ++nj)
                vf[nj] = *(const bf16x8*)(
                    kvtb + (size_t)(w * 128 + nj * 16 + fr) * S_ + tbase);
            bf16x8 pa[4];
            #pragma unroll
            for (int mi = 0; mi < 4; ++mi) {
                int r = mi * 16 + fr;
                pa[mi] = *(const bf16x8*)(
                    &Ps[r * KB + (((ksl * 4 + fg) ^ (r & 7)) << 3)]);
            }
            #pragma unroll
            for (int mi = 0; mi < 4; ++mi)
                #pragma unroll
                for (int nj = 0; nj < 8; ++nj)
                    acc[mi][nj] = mfma16(pa[mi], vf[nj], acc[mi][nj]);
        }
        // barrier C: next K tile arrived; P~ reads done before next-iter writes
        asm volatile("s_waitcnt vmcnt(0)" ::: "memory");
        __builtin_amdgcn_s_barrier();
        __builtin_amdgcn_sched_barrier(0);
        cur ^= 1;
    }
    // reduce row-sums: over fr lanes, then over the 4 sn-waves via LDS
    #pragma unroll
    for (int mi2 = 0; mi2 < 2; ++mi2)
        #pragma unroll
        for (int jj = 0; jj < 4; ++jj) {
            float v = lsum[mi2][jj];
            v += __shfl_xor(v, 1);
            v += __shfl_xor(v, 2);
            v += __shfl_xor(v, 4);
            v += __shfl_xor(v, 8);
            if (fr == 0)
                lpar[sm2 * 32 + mi2 * 16 + fg * 4 + jj][sn] = v;
        }
    __syncthreads();
    if (t < QB)
        linv[t] = 1.f / (lpar[t][0] + lpar[t][1] + lpar[t][2] + lpar[t][3]);
    __syncthreads();
    __bf16* ob = att + (size_t)hl * S_ * D_;
    #pragma unroll
    for (int mi = 0; mi < 4; ++mi)
        #pragma unroll
        for (int jj = 0; jj < 4; ++jj) {
            int srow = mi * 16 + fg * 4 + jj;
            float il = linv[srow];
            int m = qt * QB + srow;
            #pragma unroll
            for (int nj = 0; nj < 8; ++nj)
                ob[(size_t)m * D_ + w * 128 + nj * 16 + fr] =
                    (__bf16)(acc[mi][nj][jj] * il);
        }
}

// ---------------- per-head Wo GEMM + bias + relu partials, 256^2 8-phase ----------------
__global__ __launch_bounds__(512) void k_headsum(
    const __bf16* __restrict__ att, const __bf16* __restrict__ Wot,
    const float* __restrict__ bo, float* __restrict__ asum,
    int hb0, int accum) {
    __shared__ __bf16 L[2][4][8192];
    int p = blockIdx.z;
    int mt = blockIdx.y, n0 = blockIdx.x * 256;
    int m0 = mt * 256;
    int habs = hb0 + p;
    int t = threadIdx.x, lane = t & 63, w = t >> 6;
    int wr = w >> 2, wc = w & 3;
    int fr = lane & 15, fg = lane >> 4;
    const __bf16* Ab = att + ((size_t)p * S_ + m0) * D_;
    const __bf16* Bb = Wot + ((size_t)habs * D_ + n0) * D_;
    float bv4[4];
    #pragma unroll
    for (int j = 0; j < 4; ++j)
        bv4[j] = bo[(size_t)habs * D_ + n0 + wc * 64 + j * 16 + fr];
    f32x4 acc[8][4] = {};
    auto stg = [&](int tt, int h, int buf) {
        const __bf16* s = (h < 2) ? (Ab + (size_t)(h * 128) * D_ + tt * 64)
                                  : (Bb + (size_t)((h - 2) * 128) * D_ + tt * 64);
        stage_half(s, D_, &L[buf][h][0], w, lane);
    };
    auto loads = [&](const __bf16* Ah, const __bf16* Bh, int rb0, int mh, int nh,
                     bf16x8 (&af)[4][2], bf16x8 (&bv)[2][2]) {
        #pragma unroll
        for (int i = 0; i < 4; ++i)
            #pragma unroll
            for (int ks = 0; ks < 2; ++ks)
                af[i][ks] = fragS(Ah, mh * 64 + i * 16 + fr, ks, fg);
        #pragma unroll
        for (int j = 0; j < 2; ++j)
            #pragma unroll
            for (int ks = 0; ks < 2; ++ks)
                bv[j][ks] = fragS(Bh, rb0 + nh * 32 + j * 16 + fr, ks, fg);
    };
    stg(0, 0, 0); stg(0, 1, 0); stg(0, 2, 0); stg(0, 3, 0);
    int cur = 0;
    const int nt = D_ / 64;
    for (int tt = 0; tt < nt; ++tt) {
        bool pre = (tt + 1 < nt);
        const __bf16* Ah = &L[cur][wr][0];
        const __bf16* Bh = &L[cur][2 + (wc >> 1)][0];
        int rb0 = (wc & 1) * 64;
        #pragma unroll
        for (int ph = 0; ph < 4; ++ph) {
            const int mh = ph >> 1, nh = ph & 1;
            bf16x8 af[4][2], bv[2][2];
            if (ph == 0) {
                if (pre) {
                    stg(tt + 1, 0, cur ^ 1);
                    asm volatile("s_waitcnt vmcnt(2)" ::: "memory");
                } else {
                    asm volatile("s_waitcnt vmcnt(0)" ::: "memory");
                }
                __builtin_amdgcn_s_barrier();
                __builtin_amdgcn_sched_barrier(0);
                loads(Ah, Bh, rb0, mh, nh, af, bv);
            } else {
                loads(Ah, Bh, rb0, mh, nh, af, bv);
                if (pre) stg(tt + 1, ph, cur ^ 1);
                __builtin_amdgcn_s_barrier();
                __builtin_amdgcn_sched_barrier(0);
            }
            __builtin_amdgcn_s_setprio(1);
            #pragma unroll
            for (int i = 0; i < 4; ++i)
                #pragma unroll
                for (int j = 0; j < 2; ++j) {
                    acc[mh * 4 + i][nh * 2 + j] =
                        mfma16(af[i][0], bv[j][0], acc[mh * 4 + i][nh * 2 + j]);
                    acc[mh * 4 + i][nh * 2 + j] =
                        mfma16(af[i][1], bv[j][1], acc[mh * 4 + i][nh * 2 + j]);
                }
            __builtin_amdgcn_s_setprio(0);
            __builtin_amdgcn_sched_barrier(0);
            __builtin_amdgcn_s_barrier();
        }
        cur ^= 1;
    }
    float* dst = asum + ((size_t)p * S_ + m0) * D_;
    #pragma unroll
    for (int mi = 0; mi < 8; ++mi)
        #pragma unroll
        for (int jj = 0; jj < 4; ++jj) {
            int mr = wr * 128 + mi * 16 + fg * 4 + jj;
            #pragma unroll
            for (int nj = 0; nj < 4; ++nj) {
                int nc = n0 + wc * 64 + nj * 16 + fr;
                float v = fmaxf(acc[mi][nj][jj] + bv4[nj], 0.f);
                if (accum)
                    dst[(size_t)mr * D_ + nc] += v;
                else
                    dst[(size_t)mr * D_ + nc] = v;
            }
        }
}

// ---------------- residual + NPL-partial-sum + LayerNorm (per batch) ----------------
__global__ __launch_bounds__(256) void k_ln(
    const float* __restrict__ x1b, const float* __restrict__ parts,
    const float* __restrict__ gamma, const float* __restrict__ beta,
    float* __restrict__ outb, int NPL) {
    int row = blockIdx.x;
    size_t base = (size_t)row * D_;
    int c = threadIdx.x * 4;
    float4 a = *(const float4*)(x1b + base + c);
    float x[4] = {a.x, a.y, a.z, a.w};
    for (int p = 0; p < NPL; ++p) {
        const float4 v = *(const float4*)(parts + ((size_t)p * S_ + row) * D_ + c);
        x[0] += v.x; x[1] += v.y; x[2] += v.z; x[3] += v.w;
    }
    float sm = x[0] + x[1] + x[2] + x[3];
    float s2 = x[0] * x[0] + x[1] * x[1] + x[2] * x[2] + x[3] * x[3];
    #pragma unroll
    for (int m = 32; m >= 1; m >>= 1) {
        sm += __shfl_xor(sm, m);
        s2 += __shfl_xor(s2, m);
    }
    __shared__ float r1[4], r2[4];
    int w = threadIdx.x >> 6;
    if ((threadIdx.x & 63) == 0) { r1[w] = sm; r2[w] = s2; }
    __syncthreads();
    sm = r1[0] + r1[1] + r1[2] + r1[3];
    s2 = r2[0] + r2[1] + r2[2] + r2[3];
    float mean = sm * (1.f / D_);
    float var = s2 * (1.f / D_) - mean * mean;
    float rstd = rsqrtf(var + LN_EPS);
    #pragma unroll
    for (int jj = 0; jj < 4; ++jj)
        outb[base + c + jj] = gamma[c + jj] * (x[jj] - mean) * rstd + beta[c + jj];
}

// ---------------- host ----------------
extern "C" void kernel_launch(void* const* d_in, const int* in_sizes, int n_in,
                              void* d_out, int out_size, void* d_ws, size_t ws_size,
                              hipStream_t stream) {
    (void)in_sizes; (void)n_in; (void)out_size;
    const float* qin   = (const float*)d_in[0];
    const float* kvin  = (const float*)d_in[1];
    const float* Wq    = (const float*)d_in[2];
    const float* bq    = (const float*)d_in[3];
    const float* Wk    = (const float*)d_in[4];
    const float* bk    = (const float*)d_in[5];
    const float* Wo    = (const float*)d_in[6];
    const float* bo    = (const float*)d_in[7];
    const float* gamma = (const float*)d_in[8];
    const float* beta  = (const float*)d_in[9];
    float* out = (float*)d_out;
    char* ws = (char*)d_ws;

    size_t off = 0;
    auto alloc = [&](size_t bytes) {
        size_t o = off;
        off += (bytes + 255) & ~(size_t)255;
        return o;
    };
    size_t o_wqt = alloc((size_t)H_ * A_ * D_ * 2);
    size_t o_wkt = alloc((size_t)H_ * A_ * D_ * 2);
    size_t o_wot = alloc((size_t)H_ * D_ * D_ * 2);
    size_t o_kvt = alloc((size_t)B_ * D_ * S_ * 2);
    size_t o_qp  = alloc((size_t)B_ * S_ * H_ * A_ * 2);
    size_t o_kp  = alloc((size_t)B_ * S_ * H_ * A_ * 2);
    size_t fixed = off;

    // AG = heads per window: att[AG][S][D] bf16 + asum[AG][S][D] f32
    int AG = 1;
    for (int ag = 16; ag >= 1; ag >>= 1) {
        size_t need = fixed + (size_t)ag * S_ * D_ * 2 + (size_t)ag * S_ * D_ * 4
                    + (1u << 16);
        if (need <= ws_size) { AG = ag; break; }
    }
    size_t o_att = alloc((size_t)AG * S_ * D_ * 2);
    size_t o_as  = alloc((size_t)AG * S_ * D_ * 4);

    __bf16* wqt = (__bf16*)(ws + o_wqt);
    __bf16* wkt = (__bf16*)(ws + o_wkt);
    __bf16* wot = (__bf16*)(ws + o_wot);
    __bf16* kvt = (__bf16*)(ws + o_kvt);
    __bf16* qp  = (__bf16*)(ws + o_qp);
    __bf16* kp  = (__bf16*)(ws + o_kp);
    __bf16* att = (__bf16*)(ws + o_att);
    float*  asum = (float*)(ws + o_as);

    k_tr_cvt<<<dim3(A_ / 32, D_ / 32, H_), dim3(32, 8), 0, stream>>>(Wq, wqt, D_, A_);
    k_tr_cvt<<<dim3(A_ / 32, D_ / 32, H_), dim3(32, 8), 0, stream>>>(Wk, wkt, D_, A_);
    k_tr_cvt<<<dim3(D_ / 32, D_ / 32, H_), dim3(32, 8), 0, stream>>>(Wo, wot, D_, D_);
    k_tr_cvt<<<dim3(D_ / 32, S_ / 32, B_), dim3(32, 8), 0, stream>>>(kvin, kvt, S_, D_);
    k_proj_gemm<<<dim3(8, 64), 256, 0, stream>>>(qin, wqt, bq, 0.125f, qp);
    k_proj_gemm<<<dim3(8, 64), 256, 0, stream>>>(kvin, wkt, bk, 1.0f, kp);

    for (int b = 0; b < B_; ++b) {
        const __bf16* qpb  = qp + (size_t)b * S_ * (H_ * A_);
        const __bf16* kpb  = kp + (size_t)b * S_ * (H_ * A_);
        const __bf16* kvtb = kvt + (size_t)b * D_ * S_;
        for (int hb0 = 0; hb0 < H_; hb0 += AG) {
            k_attn<<<dim3(32, AG), 512, 0, stream>>>(qpb, kpb, kvtb, att, hb0);
            k_headsum<<<dim3(D_ / 256, S_ / 256, AG), 512, 0, stream>>>(
                att, wot, bo, asum, hb0, hb0 != 0);
        }
        k_ln<<<S_, 256, 0, stream>>>(qin + (size_t)b * S_ * D_, asum, gamma, beta,
                                     out + (size_t)b * S_ * D_, AG);
    }
}

// Round 6
// 1639.708 us; speedup vs baseline: 1.7412x; 1.7412x over previous
//
#include <hip/hip_runtime.h>
#include <stdint.h>

#define B_ 4
#define S_ 2048
#define D_ 1024
#define H_ 16
#define A_ 64
#define LN_EPS 1e-3f
#define L2E 1.4426950408889634f
#define LDK 40

typedef __bf16 bf16x8 __attribute__((ext_vector_type(8)));
typedef float f32x4 __attribute__((ext_vector_type(4)));

__device__ __forceinline__ f32x4 mfma16(bf16x8 a, bf16x8 b, f32x4 c) {
    return __builtin_amdgcn_mfma_f32_16x16x32_bf16(a, b, c, 0, 0, 0);
}
__device__ __forceinline__ void glds16(const void* g, void* l) {
    __builtin_amdgcn_global_load_lds(
        (const __attribute__((address_space(1))) void*)g,
        (__attribute__((address_space(3))) void*)l, 16, 0, 0);
}

// ---- 8-phase GEMM core helpers (BK=64, 8 waves) ----
#define SWZ(slot, r) ((slot) ^ (((r) & 1) << 2) ^ (((r) >> 1) & 3))
__device__ __forceinline__ void stage_half(const __bf16* __restrict__ src, size_t ld,
                                           __bf16* lhalf, int w, int lane) {
    #pragma unroll
    for (int i = 0; i < 2; ++i) {
        int ch = w * 2 + i;
        int r = ch * 8 + (lane >> 3);
        int sl = SWZ(lane & 7, r);
        glds16(src + (size_t)r * ld + sl * 8, lhalf + ch * 512);
    }
}
__device__ __forceinline__ bf16x8 fragS(const __bf16* h, int r, int ks, int fg) {
    return *(const bf16x8*)(h + r * 64 + SWZ(ks * 4 + fg, r) * 8);
}

// ---------------- tiled transpose + f32->bf16 convert ----------------
__global__ void k_tr_cvt(const float* __restrict__ in, __bf16* __restrict__ out,
                         int R, int C) {
    __shared__ float tile[32][33];
    size_t gbase = (size_t)blockIdx.z * R * C;
    int r0 = blockIdx.y * 32, c0 = blockIdx.x * 32;
    #pragma unroll
    for (int i = threadIdx.y; i < 32; i += 8)
        tile[i][threadIdx.x] = in[gbase + (size_t)(r0 + i) * C + c0 + threadIdx.x];
    __syncthreads();
    #pragma unroll
    for (int i = threadIdx.y; i < 32; i += 8)
        out[gbase + (size_t)(c0 + i) * R + r0 + threadIdx.x] = (__bf16)tile[threadIdx.x][i];
}

// ---------------- proj staging helpers ----------------
__device__ __forceinline__ void stage128_bf16(__bf16* dst, const __bf16* src, int ld, int t) {
    #pragma unroll
    for (int i = 0; i < 2; ++i) {
        int id = t + i * 256;
        int row = id >> 2, ch = (id & 3) * 8;
        *(uint4*)(dst + row * LDK + ch) = *(const uint4*)(src + (size_t)row * ld + ch);
    }
}
__device__ __forceinline__ void stage128_f32(__bf16* dst, const float* src, int ld, int t) {
    #pragma unroll
    for (int i = 0; i < 2; ++i) {
        int id = t + i * 256;
        int row = id >> 2, ch = (id & 3) * 8;
        const float* p = src + (size_t)row * ld + ch;
        float4 f0 = *(const float4*)p;
        float4 f1 = *(const float4*)(p + 4);
        __bf16 v8[8] = {(__bf16)f0.x, (__bf16)f0.y, (__bf16)f0.z, (__bf16)f0.w,
                        (__bf16)f1.x, (__bf16)f1.y, (__bf16)f1.z, (__bf16)f1.w};
        *(uint4*)(dst + row * LDK + ch) = *(const uint4*)v8;
    }
}
template <int NI, int NJ>
__device__ __forceinline__ void mfma_tile(const __bf16* As, const __bf16* Bs,
                                          int wm, int wn, int fr, int fg,
                                          f32x4 (&acc)[NI][NJ]) {
    bf16x8 af[NI], bv[NJ];
    #pragma unroll
    for (int i = 0; i < NI; ++i)
        af[i] = *(const bf16x8*)(As + (wm + i * 16 + fr) * LDK + fg * 8);
    #pragma unroll
    for (int j = 0; j < NJ; ++j)
        bv[j] = *(const bf16x8*)(Bs + (wn + j * 16 + fr) * LDK + fg * 8);
    #pragma unroll
    for (int i = 0; i < NI; ++i)
        #pragma unroll
        for (int j = 0; j < NJ; ++j)
            acc[i][j] = mfma16(af[i], bv[j], acc[i][j]);
}

// ---------------- Q/K projection (f32 A x bf16 W^T), 128^2 tile ----------------
__global__ __launch_bounds__(256) void k_proj_gemm(
    const float* __restrict__ Af, const __bf16* __restrict__ Bt,
    const float* __restrict__ bias, float scale, __bf16* __restrict__ out) {
    __shared__ __bf16 As[128 * LDK];
    __shared__ __bf16 Bs[128 * LDK];
    int m0 = blockIdx.y * 128, n0 = blockIdx.x * 128;
    int t = threadIdx.x, lane = t & 63, w = t >> 6;
    int wm = (w >> 1) * 64, wn = (w & 1) * 64;
    int fr = lane & 15, fg = lane >> 4;
    f32x4 acc[4][4] = {};
    for (int k0 = 0; k0 < D_; k0 += 32) {
        __syncthreads();
        stage128_f32(As, Af + (size_t)m0 * D_ + k0, D_, t);
        stage128_bf16(Bs, Bt + (size_t)n0 * D_ + k0, D_, t);
        __syncthreads();
        mfma_tile<4, 4>(As, Bs, wm, wn, fr, fg, acc);
    }
    #pragma unroll
    for (int j = 0; j < 4; ++j) {
        int n = n0 + wn + j * 16 + fr;
        float bv = bias[n];
        #pragma unroll
        for (int i = 0; i < 4; ++i)
            #pragma unroll
            for (int jj = 0; jj < 4; ++jj) {
                int m = m0 + wm + i * 16 + fg * 4 + jj;
                out[(size_t)m * (H_ * A_) + n] = (__bf16)((acc[i][j][jj] + bv) * scale);
            }
    }
}

// ---------------- scores + exp + row-sum; coalesced P store via LDS ----------------
__global__ __launch_bounds__(256) void k_scores(
    const __bf16* __restrict__ qpb, const __bf16* __restrict__ kpb,
    __bf16* __restrict__ P, float* __restrict__ invl, int hg0) {
    __shared__ __bf16 Qs[64 * 72];
    __shared__ __bf16 Ks[64 * 72];
    __shared__ __bf16 Ps[64 * 72];
    int qt = blockIdx.x;
    int hl = blockIdx.y;
    int h = hg0 + hl;
    int s0 = qt * 64;
    int t = threadIdx.x, lane = t & 63, w = t >> 6;
    int fr = lane & 15, fg = lane >> 4;
    __bf16* Pb = P + (size_t)hl * S_ * S_;
    float* ilb = invl + (size_t)hl * S_;
    #pragma unroll
    for (int i = 0; i < 2; ++i) {
        int id = t + i * 256;
        int row = id >> 3, ch = (id & 7) * 8;
        *(uint4*)(Qs + row * 72 + ch) =
            *(const uint4*)(qpb + (size_t)(s0 + row) * (H_ * A_) + h * A_ + ch);
    }
    float lsum[4] = {0.f, 0.f, 0.f, 0.f};
    for (int kt = 0; kt <= qt; ++kt) {
        int t0 = kt * 64;
        __syncthreads();
        #pragma unroll
        for (int i = 0; i < 2; ++i) {
            int id = t + i * 256;
            int row = id >> 3, ch = (id & 7) * 8;
            *(uint4*)(Ks + row * 72 + ch) =
                *(const uint4*)(kpb + (size_t)(t0 + row) * (H_ * A_) + h * A_ + ch);
        }
        __syncthreads();
        f32x4 sacc[4] = {};
        #pragma unroll
        for (int st = 0; st < 2; ++st) {
            bf16x8 aq = *(const bf16x8*)(Qs + (w * 16 + fr) * 72 + st * 32 + fg * 8);
            #pragma unroll
            for (int c = 0; c < 4; ++c) {
                bf16x8 bkf = *(const bf16x8*)(Ks + (c * 16 + fr) * 72 + st * 32 + fg * 8);
                sacc[c] = mfma16(aq, bkf, sacc[c]);
            }
        }
        bool diag = (kt == qt);
        #pragma unroll
        for (int c = 0; c < 4; ++c) {
            int tg = t0 + c * 16 + fr;
            #pragma unroll
            for (int jj = 0; jj < 4; ++jj) {
                int sg = s0 + w * 16 + fg * 4 + jj;
                float p = exp2f(sacc[c][jj] * L2E);
                if (diag && tg > sg) p = 0.f;
                lsum[jj] += p;
                Ps[(w * 16 + fg * 4 + jj) * 72 + c * 16 + fr] = (__bf16)p;
            }
        }
        __syncthreads();
        #pragma unroll
        for (int i = 0; i < 2; ++i) {
            int id = t + i * 256;
            int row = id >> 3, ch = (id & 7) * 8;
            *(uint4*)(Pb + (size_t)(s0 + row) * S_ + t0 + ch) =
                *(const uint4*)(Ps + row * 72 + ch);
        }
    }
    // zero-fill past the diagonal up to the next 256 boundary
    int ktEnd = ((qt >> 2) + 1) << 2;
    for (int kt2 = qt + 1; kt2 < ktEnd; ++kt2) {
        int t0 = kt2 * 64;
        uint4 z = {0, 0, 0, 0};
        #pragma unroll
        for (int i = 0; i < 2; ++i) {
            int id = t + i * 256;
            int row = id >> 3, ch = (id & 7) * 8;
            *(uint4*)(Pb + (size_t)(s0 + row) * S_ + t0 + ch) = z;
        }
    }
    #pragma unroll
    for (int jj = 0; jj < 4; ++jj) {
        float v = lsum[jj];
        v += __shfl_xor(v, 1);
        v += __shfl_xor(v, 2);
        v += __shfl_xor(v, 4);
        v += __shfl_xor(v, 8);
        if (fr == 0)
            ilb[s0 + w * 16 + fg * 4 + jj] = 1.f / v;
    }
}

// ---------------- P @ V, diagonal-PAIRED 128x256 8-phase, 1/l epilogue ----------------
// block (n0, yp, hl): two segments mt=yp and mt=15-yp -> uniform 34 K-tiles.
__global__ __launch_bounds__(512) void k_pv(
    const __bf16* __restrict__ P, const __bf16* __restrict__ kvtb,
    const float* __restrict__ invl, __bf16* __restrict__ att, int aslot0) {
    __shared__ __bf16 L[2][3][8192];  // [buf][A, B0, B1], each [128][64]
    int hl = blockIdx.z;
    int yp = blockIdx.y;
    int n0 = blockIdx.x * 256;
    int t = threadIdx.x, lane = t & 63, w = t >> 6;
    int wr = w >> 2, wc = w & 3;
    int fr = lane & 15, fg = lane >> 4;
    const __bf16* Pb = P + (size_t)hl * S_ * S_;
    const __bf16* Bb = kvtb + (size_t)n0 * S_;
    const float* ilb = invl + (size_t)hl * S_;
    __bf16* ob = att + (size_t)(aslot0 + hl) * S_ * D_;
    #pragma unroll 1
    for (int seg = 0; seg < 2; ++seg) {
        int mt = seg ? (15 - yp) : yp;
        int m0 = mt * 128;
        int nt = (mt + 1) * 2;
        const __bf16* Ab = Pb + (size_t)m0 * S_;
        f32x4 acc[4][4] = {};
        // prologue: stage tile 0 (A half + 2 B halves)
        stage_half(Ab, S_, &L[0][0][0], w, lane);
        stage_half(Bb, S_, &L[0][1][0], w, lane);
        stage_half(Bb + (size_t)128 * S_, S_, &L[0][2][0], w, lane);
        int cur = 0;
        for (int tt = 0; tt < nt; ++tt) {
            bool pre = (tt + 1 < nt);
            #pragma unroll
            for (int ph = 0; ph < 4; ++ph) {
                const int mh = ph >> 1, nh = ph & 1;
                bf16x8 af[2][2], bv[2][2];
                const __bf16* Ah = &L[cur][0][0];
                const __bf16* Bh = &L[cur][1 + (wc >> 1)][0];
                if (ph == 0) {
                    if (pre) {
                        stage_half(Ab + (tt + 1) * 64, S_, &L[cur ^ 1][0][0], w, lane);
                        asm volatile("s_waitcnt vmcnt(2)" ::: "memory");
                    } else {
                        asm volatile("s_waitcnt vmcnt(0)" ::: "memory");
                    }
                    __builtin_amdgcn_s_barrier();
                    __builtin_amdgcn_sched_barrier(0);
                    #pragma unroll
                    for (int i = 0; i < 2; ++i)
                        #pragma unroll
                        for (int ks = 0; ks < 2; ++ks)
                            af[i][ks] = fragS(Ah, wr * 64 + (mh * 2 + i) * 16 + fr, ks, fg);
                    #pragma unroll
                    for (int j = 0; j < 2; ++j)
                        #pragma unroll
                        for (int ks = 0; ks < 2; ++ks)
                            bv[j][ks] = fragS(Bh, (wc & 1) * 64 + (nh * 2 + j) * 16 + fr, ks, fg);
                } else {
                    #pragma unroll
                    for (int i = 0; i < 2; ++i)
                        #pragma unroll
                        for (int ks = 0; ks < 2; ++ks)
                            af[i][ks] = fragS(Ah, wr * 64 + (mh * 2 + i) * 16 + fr, ks, fg);
                    #pragma unroll
                    for (int j = 0; j < 2; ++j)
                        #pragma unroll
                        for (int ks = 0; ks < 2; ++ks)
                            bv[j][ks] = fragS(Bh, (wc & 1) * 64 + (nh * 2 + j) * 16 + fr, ks, fg);
                    if (pre) {
                        if (ph == 1)
                            stage_half(Bb + (tt + 1) * 64, S_, &L[cur ^ 1][1][0], w, lane);
                        else if (ph == 2)
                            stage_half(Bb + (size_t)128 * S_ + (tt + 1) * 64, S_,
                                       &L[cur ^ 1][2][0], w, lane);
                    }
                    __builtin_amdgcn_s_barrier();
                    __builtin_amdgcn_sched_barrier(0);
                }
                __builtin_amdgcn_s_setprio(1);
                #pragma unroll
                for (int i = 0; i < 2; ++i)
                    #pragma unroll
                    for (int j = 0; j < 2; ++j) {
                        acc[mh * 2 + i][nh * 2 + j] =
                            mfma16(af[i][0], bv[j][0], acc[mh * 2 + i][nh * 2 + j]);
                        acc[mh * 2 + i][nh * 2 + j] =
                            mfma16(af[i][1], bv[j][1], acc[mh * 2 + i][nh * 2 + j]);
                    }
                __builtin_amdgcn_s_setprio(0);
                __builtin_amdgcn_sched_barrier(0);
                __builtin_amdgcn_s_barrier();
            }
            cur ^= 1;
        }
        // epilogue: scale by 1/l, store
        #pragma unroll
        for (int mi = 0; mi < 4; ++mi)
            #pragma unroll
            for (int jj = 0; jj < 4; ++jj) {
                int m = m0 + wr * 64 + mi * 16 + fg * 4 + jj;
                float il = ilb[m];
                #pragma unroll
                for (int nj = 0; nj < 4; ++nj) {
                    int n = n0 + wc * 64 + nj * 16 + fr;
                    ob[(size_t)m * D_ + n] = (__bf16)(acc[mi][nj][jj] * il);
                }
            }
    }
}

// ---------------- per-head Wo GEMM + bias + relu partials, 256^2 8-phase ----------------
__global__ __launch_bounds__(512) void k_headsum(
    const __bf16* __restrict__ att, const __bf16* __restrict__ Wot,
    const float* __restrict__ bo, float* __restrict__ asum,
    int hb0, int accum) {
    __shared__ __bf16 L[2][4][8192];
    int p = blockIdx.z;
    int mt = blockIdx.y, n0 = blockIdx.x * 256;
    int m0 = mt * 256;
    int habs = hb0 + p;
    int t = threadIdx.x, lane = t & 63, w = t >> 6;
    int wr = w >> 2, wc = w & 3;
    int fr = lane & 15, fg = lane >> 4;
    const __bf16* Ab = att + ((size_t)p * S_ + m0) * D_;
    const __bf16* Bb = Wot + ((size_t)habs * D_ + n0) * D_;
    float bv4[4];
    #pragma unroll
    for (int j = 0; j < 4; ++j)
        bv4[j] = bo[(size_t)habs * D_ + n0 + wc * 64 + j * 16 + fr];
    f32x4 acc[8][4] = {};
    auto stg = [&](int tt, int h, int buf) {
        const __bf16* s = (h < 2) ? (Ab + (size_t)(h * 128) * D_ + tt * 64)
                                  : (Bb + (size_t)((h - 2) * 128) * D_ + tt * 64);
        stage_half(s, D_, &L[buf][h][0], w, lane);
    };
    auto loads = [&](const __bf16* Ah, const __bf16* Bh, int rb0, int mh, int nh,
                     bf16x8 (&af)[4][2], bf16x8 (&bv)[2][2]) {
        #pragma unroll
        for (int i = 0; i < 4; ++i)
            #pragma unroll
            for (int ks = 0; ks < 2; ++ks)
                af[i][ks] = fragS(Ah, mh * 64 + i * 16 + fr, ks, fg);
        #pragma unroll
        for (int j = 0; j < 2; ++j)
            #pragma unroll
            for (int ks = 0; ks < 2; ++ks)
                bv[j][ks] = fragS(Bh, rb0 + nh * 32 + j * 16 + fr, ks, fg);
    };
    stg(0, 0, 0); stg(0, 1, 0); stg(0, 2, 0); stg(0, 3, 0);
    int cur = 0;
    const int nt = D_ / 64;
    for (int tt = 0; tt < nt; ++tt) {
        bool pre = (tt + 1 < nt);
        const __bf16* Ah = &L[cur][wr][0];
        const __bf16* Bh = &L[cur][2 + (wc >> 1)][0];
        int rb0 = (wc & 1) * 64;
        #pragma unroll
        for (int ph = 0; ph < 4; ++ph) {
            const int mh = ph >> 1, nh = ph & 1;
            bf16x8 af[4][2], bv[2][2];
            if (ph == 0) {
                if (pre) {
                    stg(tt + 1, 0, cur ^ 1);
                    asm volatile("s_waitcnt vmcnt(2)" ::: "memory");
                } else {
                    asm volatile("s_waitcnt vmcnt(0)" ::: "memory");
                }
                __builtin_amdgcn_s_barrier();
                __builtin_amdgcn_sched_barrier(0);
                loads(Ah, Bh, rb0, mh, nh, af, bv);
            } else {
                loads(Ah, Bh, rb0, mh, nh, af, bv);
                if (pre) stg(tt + 1, ph, cur ^ 1);
                __builtin_amdgcn_s_barrier();
                __builtin_amdgcn_sched_barrier(0);
            }
            __builtin_amdgcn_s_setprio(1);
            #pragma unroll
            for (int i = 0; i < 4; ++i)
                #pragma unroll
                for (int j = 0; j < 2; ++j) {
                    acc[mh * 4 + i][nh * 2 + j] =
                        mfma16(af[i][0], bv[j][0], acc[mh * 4 + i][nh * 2 + j]);
                    acc[mh * 4 + i][nh * 2 + j] =
                        mfma16(af[i][1], bv[j][1], acc[mh * 4 + i][nh * 2 + j]);
                }
            __builtin_amdgcn_s_setprio(0);
            __builtin_amdgcn_sched_barrier(0);
            __builtin_amdgcn_s_barrier();
        }
        cur ^= 1;
    }
    float* dst = asum + ((size_t)p * S_ + m0) * D_;
    #pragma unroll
    for (int mi = 0; mi < 8; ++mi)
        #pragma unroll
        for (int jj = 0; jj < 4; ++jj) {
            int mr = wr * 128 + mi * 16 + fg * 4 + jj;
            #pragma unroll
            for (int nj = 0; nj < 4; ++nj) {
                int nc = n0 + wc * 64 + nj * 16 + fr;
                float v = fmaxf(acc[mi][nj][jj] + bv4[nj], 0.f);
                if (accum)
                    dst[(size_t)mr * D_ + nc] += v;
                else
                    dst[(size_t)mr * D_ + nc] = v;
            }
        }
}

// ---------------- residual + NPL-partial-sum + LayerNorm (per batch) ----------------
__global__ __launch_bounds__(256) void k_ln(
    const float* __restrict__ x1b, const float* __restrict__ parts,
    const float* __restrict__ gamma, const float* __restrict__ beta,
    float* __restrict__ outb, int NPL) {
    int row = blockIdx.x;
    size_t base = (size_t)row * D_;
    int c = threadIdx.x * 4;
    float4 a = *(const float4*)(x1b + base + c);
    float x[4] = {a.x, a.y, a.z, a.w};
    for (int p = 0; p < NPL; ++p) {
        const float4 v = *(const float4*)(parts + ((size_t)p * S_ + row) * D_ + c);
        x[0] += v.x; x[1] += v.y; x[2] += v.z; x[3] += v.w;
    }
    float sm = x[0] + x[1] + x[2] + x[3];
    float s2 = x[0] * x[0] + x[1] * x[1] + x[2] * x[2] + x[3] * x[3];
    #pragma unroll
    for (int m = 32; m >= 1; m >>= 1) {
        sm += __shfl_xor(sm, m);
        s2 += __shfl_xor(s2, m);
    }
    __shared__ float r1[4], r2[4];
    int w = threadIdx.x >> 6;
    if ((threadIdx.x & 63) == 0) { r1[w] = sm; r2[w] = s2; }
    __syncthreads();
    sm = r1[0] + r1[1] + r1[2] + r1[3];
    s2 = r2[0] + r2[1] + r2[2] + r2[3];
    float mean = sm * (1.f / D_);
    float var = s2 * (1.f / D_) - mean * mean;
    float rstd = rsqrtf(var + LN_EPS);
    #pragma unroll
    for (int jj = 0; jj < 4; ++jj)
        outb[base + c + jj] = gamma[c + jj] * (x[jj] - mean) * rstd + beta[c + jj];
}

// ---------------- host ----------------
extern "C" void kernel_launch(void* const* d_in, const int* in_sizes, int n_in,
                              void* d_out, int out_size, void* d_ws, size_t ws_size,
                              hipStream_t stream) {
    (void)in_sizes; (void)n_in; (void)out_size;
    const float* qin   = (const float*)d_in[0];
    const float* kvin  = (const float*)d_in[1];
    const float* Wq    = (const float*)d_in[2];
    const float* bq    = (const float*)d_in[3];
    const float* Wk    = (const float*)d_in[4];
    const float* bk    = (const float*)d_in[5];
    const float* Wo    = (const float*)d_in[6];
    const float* bo    = (const float*)d_in[7];
    const float* gamma = (const float*)d_in[8];
    const float* beta  = (const float*)d_in[9];
    float* out = (float*)d_out;
    char* ws = (char*)d_ws;

    size_t off = 0;
    auto alloc = [&](size_t bytes) {
        size_t o = off;
        off += (bytes + 255) & ~(size_t)255;
        return o;
    };
    size_t o_wqt = alloc((size_t)H_ * A_ * D_ * 2);
    size_t o_wkt = alloc((size_t)H_ * A_ * D_ * 2);
    size_t o_wot = alloc((size_t)H_ * D_ * D_ * 2);
    size_t o_kvt = alloc((size_t)B_ * D_ * S_ * 2);
    size_t o_qp  = alloc((size_t)B_ * S_ * H_ * A_ * 2);
    size_t o_kp  = alloc((size_t)B_ * S_ * H_ * A_ * 2);
    size_t fixed = off;

    // AG = heads per headsum window; HGp = heads per scores/pv dispatch.
    // P aliases asum when AG==16 (disjoint lifetimes within a window).
    int AG = 1, HGp = 1;
    {
        const int ags[6] = {16, 8, 8, 4, 2, 1};
        const int hgs[6] = {8, 8, 4, 4, 2, 1};
        for (int i = 0; i < 6; ++i) {
            int ag = ags[i], hg = hgs[i];
            size_t pB = (size_t)hg * S_ * S_ * 2;
            size_t aB = (size_t)ag * S_ * D_ * 4;
            size_t un = (ag == 16) ? (pB > aB ? pB : aB) : pB + aB;
            size_t need = fixed + (size_t)ag * S_ * D_ * 2 + un
                        + (size_t)hg * S_ * 4 + (1u << 16);
            if (need <= ws_size) { AG = ag; HGp = hg; break; }
        }
    }
    size_t o_att = alloc((size_t)AG * S_ * D_ * 2);
    size_t o_P, o_as;
    if (AG == 16) {
        size_t pB = (size_t)HGp * S_ * S_ * 2;
        size_t aB = (size_t)AG * S_ * D_ * 4;
        size_t o_un = alloc(pB > aB ? pB : aB);
        o_P = o_un; o_as = o_un;
    } else {
        o_P  = alloc((size_t)HGp * S_ * S_ * 2);
        o_as = alloc((size_t)AG * S_ * D_ * 4);
    }
    size_t o_il = alloc((size_t)HGp * S_ * 4);

    __bf16* wqt = (__bf16*)(ws + o_wqt);
    __bf16* wkt = (__bf16*)(ws + o_wkt);
    __bf16* wot = (__bf16*)(ws + o_wot);
    __bf16* kvt = (__bf16*)(ws + o_kvt);
    __bf16* qp  = (__bf16*)(ws + o_qp);
    __bf16* kp  = (__bf16*)(ws + o_kp);
    __bf16* att = (__bf16*)(ws + o_att);
    __bf16* Pp  = (__bf16*)(ws + o_P);
    float*  asum = (float*)(ws + o_as);
    float*  il  = (float*)(ws + o_il);

    k_tr_cvt<<<dim3(A_ / 32, D_ / 32, H_), dim3(32, 8), 0, stream>>>(Wq, wqt, D_, A_);
    k_tr_cvt<<<dim3(A_ / 32, D_ / 32, H_), dim3(32, 8), 0, stream>>>(Wk, wkt, D_, A_);
    k_tr_cvt<<<dim3(D_ / 32, D_ / 32, H_), dim3(32, 8), 0, stream>>>(Wo, wot, D_, D_);
    k_tr_cvt<<<dim3(D_ / 32, S_ / 32, B_), dim3(32, 8), 0, stream>>>(kvin, kvt, S_, D_);
    k_proj_gemm<<<dim3(8, 64), 256, 0, stream>>>(qin, wqt, bq, 0.125f, qp);
    k_proj_gemm<<<dim3(8, 64), 256, 0, stream>>>(kvin, wkt, bk, 1.0f, kp);

    for (int b = 0; b < B_; ++b) {
        const __bf16* qpb  = qp + (size_t)b * S_ * (H_ * A_);
        const __bf16* kpb  = kp + (size_t)b * S_ * (H_ * A_);
        const __bf16* kvtb = kvt + (size_t)b * D_ * S_;
        for (int hb0 = 0; hb0 < H_; hb0 += AG) {
            for (int hg0 = hb0; hg0 < hb0 + AG; hg0 += HGp) {
                k_scores<<<dim3(32, HGp), 256, 0, stream>>>(qpb, kpb, Pp, il, hg0);
                k_pv<<<dim3(D_ / 256, 8, HGp), 512, 0, stream>>>(
                    Pp, kvtb, il, att, hg0 - hb0);
            }
            k_headsum<<<dim3(D_ / 256, S_ / 256, AG), 512, 0, stream>>>(
                att, wot, bo, asum, hb0, hb0 != 0);
        }
        k_ln<<<S_, 256, 0, stream>>>(qin + (size_t)b * S_ * D_, asum, gamma, beta,
                                     out + (size_t)b * S_ * D_, AG);
    }
}

// Round 7
// 1390.166 us; speedup vs baseline: 2.0537x; 1.1795x over previous
//
#include <hip/hip_runtime.h>
#include <stdint.h>

#define B_ 4
#define S_ 2048
#define D_ 1024
#define H_ 16
#define A_ 64
#define LN_EPS 1e-3f
#define L2E 1.4426950408889634f
#define LDK 40

typedef __bf16 bf16x8 __attribute__((ext_vector_type(8)));
typedef float f32x4 __attribute__((ext_vector_type(4)));

__device__ __forceinline__ f32x4 mfma16(bf16x8 a, bf16x8 b, f32x4 c) {
    return __builtin_amdgcn_mfma_f32_16x16x32_bf16(a, b, c, 0, 0, 0);
}
__device__ __forceinline__ void glds16(const void* g, void* l) {
    __builtin_amdgcn_global_load_lds(
        (const __attribute__((address_space(1))) void*)g,
        (__attribute__((address_space(3))) void*)l, 16, 0, 0);
}

// ---- shared swizzle helpers (16B slots within [r][64] bf16 rows) ----
#define SWZ(slot, r) ((slot) ^ (((r) & 1) << 2) ^ (((r) >> 1) & 3))
// stage a [128][64] bf16 half-tile: linear LDS dest, swizzle folded into source col
__device__ __forceinline__ void stage_half(const __bf16* __restrict__ src, size_t ld,
                                           __bf16* lhalf, int w, int lane) {
    #pragma unroll
    for (int i = 0; i < 2; ++i) {
        int ch = w * 2 + i;
        int r = ch * 8 + (lane >> 3);
        int sl = SWZ(lane & 7, r);
        glds16(src + (size_t)r * ld + sl * 8, lhalf + ch * 512);
    }
}
__device__ __forceinline__ bf16x8 fragS(const __bf16* h, int r, int ks, int fg) {
    return *(const bf16x8*)(h + r * 64 + SWZ(ks * 4 + fg, r) * 8);
}

// ---------------- tiled transpose + f32->bf16 convert ----------------
__global__ void k_tr_cvt(const float* __restrict__ in, __bf16* __restrict__ out,
                         int R, int C) {
    __shared__ float tile[32][33];
    size_t gbase = (size_t)blockIdx.z * R * C;
    int r0 = blockIdx.y * 32, c0 = blockIdx.x * 32;
    #pragma unroll
    for (int i = threadIdx.y; i < 32; i += 8)
        tile[i][threadIdx.x] = in[gbase + (size_t)(r0 + i) * C + c0 + threadIdx.x];
    __syncthreads();
    #pragma unroll
    for (int i = threadIdx.y; i < 32; i += 8)
        out[gbase + (size_t)(c0 + i) * R + r0 + threadIdx.x] = (__bf16)tile[threadIdx.x][i];
}

// ---------------- proj staging helpers ----------------
__device__ __forceinline__ void stage128_bf16(__bf16* dst, const __bf16* src, int ld, int t) {
    #pragma unroll
    for (int i = 0; i < 2; ++i) {
        int id = t + i * 256;
        int row = id >> 2, ch = (id & 3) * 8;
        *(uint4*)(dst + row * LDK + ch) = *(const uint4*)(src + (size_t)row * ld + ch);
    }
}
__device__ __forceinline__ void stage128_f32(__bf16* dst, const float* src, int ld, int t) {
    #pragma unroll
    for (int i = 0; i < 2; ++i) {
        int id = t + i * 256;
        int row = id >> 2, ch = (id & 3) * 8;
        const float* p = src + (size_t)row * ld + ch;
        float4 f0 = *(const float4*)p;
        float4 f1 = *(const float4*)(p + 4);
        __bf16 v8[8] = {(__bf16)f0.x, (__bf16)f0.y, (__bf16)f0.z, (__bf16)f0.w,
                        (__bf16)f1.x, (__bf16)f1.y, (__bf16)f1.z, (__bf16)f1.w};
        *(uint4*)(dst + row * LDK + ch) = *(const uint4*)v8;
    }
}
template <int NI, int NJ>
__device__ __forceinline__ void mfma_tile(const __bf16* As, const __bf16* Bs,
                                          int wm, int wn, int fr, int fg,
                                          f32x4 (&acc)[NI][NJ]) {
    bf16x8 af[NI], bv[NJ];
    #pragma unroll
    for (int i = 0; i < NI; ++i)
        af[i] = *(const bf16x8*)(As + (wm + i * 16 + fr) * LDK + fg * 8);
    #pragma unroll
    for (int j = 0; j < NJ; ++j)
        bv[j] = *(const bf16x8*)(Bs + (wn + j * 16 + fr) * LDK + fg * 8);
    #pragma unroll
    for (int i = 0; i < NI; ++i)
        #pragma unroll
        for (int j = 0; j < NJ; ++j)
            acc[i][j] = mfma16(af[i], bv[j], acc[i][j]);
}

// ---------------- Q/K projection (f32 A x bf16 W^T), 128^2 tile ----------------
__global__ __launch_bounds__(256) void k_proj_gemm(
    const float* __restrict__ Af, const __bf16* __restrict__ Bt,
    const float* __restrict__ bias, float scale, __bf16* __restrict__ out) {
    __shared__ __bf16 As[128 * LDK];
    __shared__ __bf16 Bs[128 * LDK];
    int m0 = blockIdx.y * 128, n0 = blockIdx.x * 128;
    int t = threadIdx.x, lane = t & 63, w = t >> 6;
    int wm = (w >> 1) * 64, wn = (w & 1) * 64;
    int fr = lane & 15, fg = lane >> 4;
    f32x4 acc[4][4] = {};
    for (int k0 = 0; k0 < D_; k0 += 32) {
        __syncthreads();
        stage128_f32(As, Af + (size_t)m0 * D_ + k0, D_, t);
        stage128_bf16(Bs, Bt + (size_t)n0 * D_ + k0, D_, t);
        __syncthreads();
        mfma_tile<4, 4>(As, Bs, wm, wn, fr, fg, acc);
    }
    #pragma unroll
    for (int j = 0; j < 4; ++j) {
        int n = n0 + wn + j * 16 + fr;
        float bv = bias[n];
        #pragma unroll
        for (int i = 0; i < 4; ++i)
            #pragma unroll
            for (int jj = 0; jj < 4; ++jj) {
                int m = m0 + wm + i * 16 + fg * 4 + jj;
                out[(size_t)m * (H_ * A_) + n] = (__bf16)((acc[i][j][jj] + bv) * scale);
            }
    }
}

// ---------------- fused flash attention: QK^T -> exp -> PV, staged, paired ----------------
// block (n0/256, yp, hl): segments mt=yp and mt=15-yp (uniform 34 K-tiles of 64).
// Per seg: Q[128][64] hoisted to regs; K [64][64] + V [2][128][64] glds-staged,
// double-buffered, counted vmcnt; P~ [128][64] LDS-only (write swizzle col^=fg<<4).
__global__ __launch_bounds__(512) void k_fattn(
    const __bf16* __restrict__ qpb, const __bf16* __restrict__ kpb,
    const __bf16* __restrict__ kvtb, __bf16* __restrict__ att, int hb0) {
    __shared__ __bf16 Ks[2][64 * 64];
    __shared__ __bf16 Vs[2][2][128 * 64];
    __shared__ __bf16 Ps[128 * 64];
    __shared__ float lpar[128][2];
    int hl = blockIdx.z;
    int h = hb0 + hl;
    int yp = blockIdx.y;
    int n0 = blockIdx.x * 256;
    int t = threadIdx.x, lane = t & 63, w = t >> 6;
    int fr = lane & 15, fg = lane >> 4;
    int wr = w >> 2, wc = w & 3;   // PV role: rows wr*64, cols wc*64
    int sr = w >> 1, sc = w & 1;   // QK^T role: q-rows sr*32, kv-cols sc*32
    const __bf16* Vb = kvtb + (size_t)n0 * S_;
    __bf16* ob = att + (size_t)hl * S_ * D_;

    #pragma unroll 1
    for (int seg = 0; seg < 2; ++seg) {
        int mt = seg ? (15 - yp) : yp;
        int m0 = mt * 128;
        int NT = (mt + 1) * 2;
        // ---- prologue: Q -> Ps -> regs; K0; V0 halves ----
        stage_half(qpb + (size_t)m0 * (H_ * A_) + h * A_, H_ * A_, Ps, w, lane);
        {
            int r = w * 8 + (lane >> 3);
            glds16(kpb + (size_t)r * (H_ * A_) + h * A_ + SWZ(lane & 7, r) * 8,
                   &Ks[0][w * 512]);
        }
        asm volatile("s_waitcnt vmcnt(0)" ::: "memory");
        __builtin_amdgcn_s_barrier();
        bf16x8 qf[2][2];
        #pragma unroll
        for (int mi = 0; mi < 2; ++mi)
            #pragma unroll
            for (int ks = 0; ks < 2; ++ks)
                qf[mi][ks] = fragS(Ps, sr * 32 + mi * 16 + fr, ks, fg);
        asm volatile("s_waitcnt lgkmcnt(0)" ::: "memory");
        stage_half(Vb, S_, &Vs[0][0][0], w, lane);
        stage_half(Vb + (size_t)128 * S_, S_, &Vs[0][1][0], w, lane);
        __builtin_amdgcn_s_barrier();  // Q reads done before P~ writes
        __builtin_amdgcn_sched_barrier(0);
        f32x4 acc[4][4] = {};
        float lsum[2][4] = {};
        int cur = 0;
        for (int tt = 0; tt < NT; ++tt) {
            bool pre = (tt + 1 < NT);
            // ---- phase A: QK^T + exp + P~ store (issue K_next early) ----
            if (pre) {
                int r = w * 8 + (lane >> 3);
                glds16(kpb + (size_t)((tt + 1) * 64 + r) * (H_ * A_) + h * A_ +
                           SWZ(lane & 7, r) * 8,
                       &Ks[cur ^ 1][w * 512]);
                asm volatile("s_waitcnt vmcnt(5)" ::: "memory");
            } else {
                asm volatile("s_waitcnt vmcnt(4)" ::: "memory");
            }
            __builtin_amdgcn_s_barrier();
            __builtin_amdgcn_sched_barrier(0);
            f32x4 sac[2][2] = {};
            __builtin_amdgcn_s_setprio(1);
            #pragma unroll
            for (int ks = 0; ks < 2; ++ks)
                #pragma unroll
                for (int nj = 0; nj < 2; ++nj) {
                    bf16x8 kf = fragS(&Ks[cur][0], sc * 32 + nj * 16 + fr, ks, fg);
                    #pragma unroll
                    for (int mi = 0; mi < 2; ++mi)
                        sac[mi][nj] = mfma16(qf[mi][ks], kf, sac[mi][nj]);
                }
            __builtin_amdgcn_s_setprio(0);
            bool dg = (tt >= 2 * mt);
            #pragma unroll
            for (int mi = 0; mi < 2; ++mi)
                #pragma unroll
                for (int nj = 0; nj < 2; ++nj)
                    #pragma unroll
                    for (int jj = 0; jj < 4; ++jj) {
                        int srow = sr * 32 + mi * 16 + fg * 4 + jj;
                        int col = sc * 32 + nj * 16 + fr;
                        float p = exp2f(sac[mi][nj][jj] * L2E);
                        if (dg && (tt * 64 + col > m0 + srow)) p = 0.f;
                        lsum[mi][jj] += p;
                        Ps[srow * 64 + (col ^ (fg << 4))] = (__bf16)p;
                    }
            asm volatile("s_waitcnt lgkmcnt(0)" ::: "memory");
            __builtin_amdgcn_s_barrier();
            __builtin_amdgcn_sched_barrier(0);
            // ---- phase B: PV (issue V_next early) ----
            if (pre) {
                stage_half(Vb + (tt + 1) * 64, S_, &Vs[cur ^ 1][0][0], w, lane);
                stage_half(Vb + (size_t)128 * S_ + (tt + 1) * 64, S_,
                           &Vs[cur ^ 1][1][0], w, lane);
                asm volatile("s_waitcnt vmcnt(5)" ::: "memory");
            } else {
                asm volatile("s_waitcnt vmcnt(0)" ::: "memory");
            }
            __builtin_amdgcn_s_barrier();
            __builtin_amdgcn_sched_barrier(0);
            __builtin_amdgcn_s_setprio(1);
            const __bf16* Vh = &Vs[cur][wc >> 1][0];
            #pragma unroll
            for (int ks = 0; ks < 2; ++ks) {
                bf16x8 pa[4], vf[4];
                #pragma unroll
                for (int mi = 0; mi < 4; ++mi) {
                    int r = wr * 64 + mi * 16 + fr;
                    int g = (ks * 4 + fg) ^ (((fr >> 2) & 3) << 1);
                    pa[mi] = *(const bf16x8*)(Ps + r * 64 + g * 8);
                }
                #pragma unroll
                for (int nj = 0; nj < 4; ++nj)
                    vf[nj] = fragS(Vh, (wc & 1) * 64 + nj * 16 + fr, ks, fg);
                #pragma unroll
                for (int mi = 0; mi < 4; ++mi)
                    #pragma unroll
                    for (int nj = 0; nj < 4; ++nj)
                        acc[mi][nj] = mfma16(pa[mi], vf[nj], acc[mi][nj]);
            }
            __builtin_amdgcn_s_setprio(0);
            __builtin_amdgcn_sched_barrier(0);
            cur ^= 1;
        }
        // ---- row sums: shfl over fr, combine 2 col-waves via LDS ----
        #pragma unroll
        for (int mi = 0; mi < 2; ++mi)
            #pragma unroll
            for (int jj = 0; jj < 4; ++jj) {
                float v = lsum[mi][jj];
                v += __shfl_xor(v, 1);
                v += __shfl_xor(v, 2);
                v += __shfl_xor(v, 4);
                v += __shfl_xor(v, 8);
                if (fr == 0) lpar[sr * 32 + mi * 16 + fg * 4 + jj][sc] = v;
            }
        asm volatile("s_waitcnt lgkmcnt(0)" ::: "memory");
        __builtin_amdgcn_s_barrier();
        // ---- epilogue: normalize + store ----
        #pragma unroll
        for (int mi = 0; mi < 4; ++mi)
            #pragma unroll
            for (int jj = 0; jj < 4; ++jj) {
                int row = wr * 64 + mi * 16 + fg * 4 + jj;
                float il = 1.f / (lpar[row][0] + lpar[row][1]);
                int m = m0 + row;
                #pragma unroll
                for (int nj = 0; nj < 4; ++nj) {
                    int n = n0 + wc * 64 + nj * 16 + fr;
                    ob[(size_t)m * D_ + n] = (__bf16)(acc[mi][nj][jj] * il);
                }
            }
        __builtin_amdgcn_s_barrier();  // Ps/lpar reuse across segs
    }
}

// ---------------- per-head Wo GEMM + bias + relu partials, 256^2 8-phase ----------------
__global__ __launch_bounds__(512) void k_headsum(
    const __bf16* __restrict__ att, const __bf16* __restrict__ Wot,
    const float* __restrict__ bo, float* __restrict__ asum,
    int hb0, int accum) {
    __shared__ __bf16 L[2][4][8192];
    int p = blockIdx.z;
    int mt = blockIdx.y, n0 = blockIdx.x * 256;
    int m0 = mt * 256;
    int habs = hb0 + p;
    int t = threadIdx.x, lane = t & 63, w = t >> 6;
    int wr = w >> 2, wc = w & 3;
    int fr = lane & 15, fg = lane >> 4;
    const __bf16* Ab = att + ((size_t)p * S_ + m0) * D_;
    const __bf16* Bb = Wot + ((size_t)habs * D_ + n0) * D_;
    float bv4[4];
    #pragma unroll
    for (int j = 0; j < 4; ++j)
        bv4[j] = bo[(size_t)habs * D_ + n0 + wc * 64 + j * 16 + fr];
    f32x4 acc[8][4] = {};
    auto stg = [&](int tt, int h, int buf) {
        const __bf16* s = (h < 2) ? (Ab + (size_t)(h * 128) * D_ + tt * 64)
                                  : (Bb + (size_t)((h - 2) * 128) * D_ + tt * 64);
        stage_half(s, D_, &L[buf][h][0], w, lane);
    };
    auto loads = [&](const __bf16* Ah, const __bf16* Bh, int rb0, int mh, int nh,
                     bf16x8 (&af)[4][2], bf16x8 (&bv)[2][2]) {
        #pragma unroll
        for (int i = 0; i < 4; ++i)
            #pragma unroll
            for (int ks = 0; ks < 2; ++ks)
                af[i][ks] = fragS(Ah, mh * 64 + i * 16 + fr, ks, fg);
        #pragma unroll
        for (int j = 0; j < 2; ++j)
            #pragma unroll
            for (int ks = 0; ks < 2; ++ks)
                bv[j][ks] = fragS(Bh, rb0 + nh * 32 + j * 16 + fr, ks, fg);
    };
    stg(0, 0, 0); stg(0, 1, 0); stg(0, 2, 0); stg(0, 3, 0);
    int cur = 0;
    const int nt = D_ / 64;
    for (int tt = 0; tt < nt; ++tt) {
        bool pre = (tt + 1 < nt);
        const __bf16* Ah = &L[cur][wr][0];
        const __bf16* Bh = &L[cur][2 + (wc >> 1)][0];
        int rb0 = (wc & 1) * 64;
        #pragma unroll
        for (int ph = 0; ph < 4; ++ph) {
            const int mh = ph >> 1, nh = ph & 1;
            bf16x8 af[4][2], bv[2][2];
            if (ph == 0) {
                // deep prefetch: issue ALL of tile tt+1 here -> full-iter latency cover
                if (pre) {
                    stg(tt + 1, 0, cur ^ 1);
                    stg(tt + 1, 1, cur ^ 1);
                    stg(tt + 1, 2, cur ^ 1);
                    stg(tt + 1, 3, cur ^ 1);
                    asm volatile("s_waitcnt vmcnt(8)" ::: "memory");
                } else {
                    asm volatile("s_waitcnt vmcnt(0)" ::: "memory");
                }
                __builtin_amdgcn_s_barrier();
                __builtin_amdgcn_sched_barrier(0);
                loads(Ah, Bh, rb0, mh, nh, af, bv);
            } else {
                loads(Ah, Bh, rb0, mh, nh, af, bv);
                __builtin_amdgcn_s_barrier();
                __builtin_amdgcn_sched_barrier(0);
            }
            __builtin_amdgcn_s_setprio(1);
            #pragma unroll
            for (int i = 0; i < 4; ++i)
                #pragma unroll
                for (int j = 0; j < 2; ++j) {
                    acc[mh * 4 + i][nh * 2 + j] =
                        mfma16(af[i][0], bv[j][0], acc[mh * 4 + i][nh * 2 + j]);
                    acc[mh * 4 + i][nh * 2 + j] =
                        mfma16(af[i][1], bv[j][1], acc[mh * 4 + i][nh * 2 + j]);
                }
            __builtin_amdgcn_s_setprio(0);
            __builtin_amdgcn_sched_barrier(0);
            __builtin_amdgcn_s_barrier();
        }
        cur ^= 1;
    }
    float* dst = asum + ((size_t)p * S_ + m0) * D_;
    #pragma unroll
    for (int mi = 0; mi < 8; ++mi)
        #pragma unroll
        for (int jj = 0; jj < 4; ++jj) {
            int mr = wr * 128 + mi * 16 + fg * 4 + jj;
            #pragma unroll
            for (int nj = 0; nj < 4; ++nj) {
                int nc = n0 + wc * 64 + nj * 16 + fr;
                float v = fmaxf(acc[mi][nj][jj] + bv4[nj], 0.f);
                if (accum)
                    dst[(size_t)mr * D_ + nc] += v;
                else
                    dst[(size_t)mr * D_ + nc] = v;
            }
        }
}

// ---------------- residual + NPL-partial-sum + LayerNorm (per batch) ----------------
__global__ __launch_bounds__(256) void k_ln(
    const float* __restrict__ x1b, const float* __restrict__ parts,
    const float* __restrict__ gamma, const float* __restrict__ beta,
    float* __restrict__ outb, int NPL) {
    int row = blockIdx.x;
    size_t base = (size_t)row * D_;
    int c = threadIdx.x * 4;
    float4 a = *(const float4*)(x1b + base + c);
    float x[4] = {a.x, a.y, a.z, a.w};
    for (int p = 0; p < NPL; ++p) {
        const float4 v = *(const float4*)(parts + ((size_t)p * S_ + row) * D_ + c);
        x[0] += v.x; x[1] += v.y; x[2] += v.z; x[3] += v.w;
    }
    float sm = x[0] + x[1] + x[2] + x[3];
    float s2 = x[0] * x[0] + x[1] * x[1] + x[2] * x[2] + x[3] * x[3];
    #pragma unroll
    for (int m = 32; m >= 1; m >>= 1) {
        sm += __shfl_xor(sm, m);
        s2 += __shfl_xor(s2, m);
    }
    __shared__ float r1[4], r2[4];
    int w = threadIdx.x >> 6;
    if ((threadIdx.x & 63) == 0) { r1[w] = sm; r2[w] = s2; }
    __syncthreads();
    sm = r1[0] + r1[1] + r1[2] + r1[3];
    s2 = r2[0] + r2[1] + r2[2] + r2[3];
    float mean = sm * (1.f / D_);
    float var = s2 * (1.f / D_) - mean * mean;
    float rstd = rsqrtf(var + LN_EPS);
    #pragma unroll
    for (int jj = 0; jj < 4; ++jj)
        outb[base + c + jj] = gamma[c + jj] * (x[jj] - mean) * rstd + beta[c + jj];
}

// ---------------- host ----------------
extern "C" void kernel_launch(void* const* d_in, const int* in_sizes, int n_in,
                              void* d_out, int out_size, void* d_ws, size_t ws_size,
                              hipStream_t stream) {
    (void)in_sizes; (void)n_in; (void)out_size;
    const float* qin   = (const float*)d_in[0];
    const float* kvin  = (const float*)d_in[1];
    const float* Wq    = (const float*)d_in[2];
    const float* bq    = (const float*)d_in[3];
    const float* Wk    = (const float*)d_in[4];
    const float* bk    = (const float*)d_in[5];
    const float* Wo    = (const float*)d_in[6];
    const float* bo    = (const float*)d_in[7];
    const float* gamma = (const float*)d_in[8];
    const float* beta  = (const float*)d_in[9];
    float* out = (float*)d_out;
    char* ws = (char*)d_ws;

    size_t off = 0;
    auto alloc = [&](size_t bytes) {
        size_t o = off;
        off += (bytes + 255) & ~(size_t)255;
        return o;
    };
    size_t o_wqt = alloc((size_t)H_ * A_ * D_ * 2);
    size_t o_wkt = alloc((size_t)H_ * A_ * D_ * 2);
    size_t o_wot = alloc((size_t)H_ * D_ * D_ * 2);
    size_t o_kvt = alloc((size_t)B_ * D_ * S_ * 2);
    size_t o_qp  = alloc((size_t)B_ * S_ * H_ * A_ * 2);
    size_t o_kp  = alloc((size_t)B_ * S_ * H_ * A_ * 2);
    size_t fixed = off;

    // AG = heads per window: att[AG][S][D] bf16 + asum[AG][S][D] f32 (no P~ anymore)
    int AG = 1;
    for (int ag = 16; ag >= 1; ag >>= 1) {
        size_t need = fixed + (size_t)ag * S_ * D_ * 2 + (size_t)ag * S_ * D_ * 4
                    + (1u << 16);
        if (need <= ws_size) { AG = ag; break; }
    }
    size_t o_att = alloc((size_t)AG * S_ * D_ * 2);
    size_t o_as  = alloc((size_t)AG * S_ * D_ * 4);

    __bf16* wqt = (__bf16*)(ws + o_wqt);
    __bf16* wkt = (__bf16*)(ws + o_wkt);
    __bf16* wot = (__bf16*)(ws + o_wot);
    __bf16* kvt = (__bf16*)(ws + o_kvt);
    __bf16* qp  = (__bf16*)(ws + o_qp);
    __bf16* kp  = (__bf16*)(ws + o_kp);
    __bf16* att = (__bf16*)(ws + o_att);
    float*  asum = (float*)(ws + o_as);

    k_tr_cvt<<<dim3(A_ / 32, D_ / 32, H_), dim3(32, 8), 0, stream>>>(Wq, wqt, D_, A_);
    k_tr_cvt<<<dim3(A_ / 32, D_ / 32, H_), dim3(32, 8), 0, stream>>>(Wk, wkt, D_, A_);
    k_tr_cvt<<<dim3(D_ / 32, D_ / 32, H_), dim3(32, 8), 0, stream>>>(Wo, wot, D_, D_);
    k_tr_cvt<<<dim3(D_ / 32, S_ / 32, B_), dim3(32, 8), 0, stream>>>(kvin, kvt, S_, D_);
    k_proj_gemm<<<dim3(8, 64), 256, 0, stream>>>(qin, wqt, bq, 0.125f, qp);
    k_proj_gemm<<<dim3(8, 64), 256, 0, stream>>>(kvin, wkt, bk, 1.0f, kp);

    for (int b = 0; b < B_; ++b) {
        const __bf16* qpb  = qp + (size_t)b * S_ * (H_ * A_);
        const __bf16* kpb  = kp + (size_t)b * S_ * (H_ * A_);
        const __bf16* kvtb = kvt + (size_t)b * D_ * S_;
        for (int hb0 = 0; hb0 < H_; hb0 += AG) {
            k_fattn<<<dim3(D_ / 256, 8, AG), 512, 0, stream>>>(qpb, kpb, kvtb, att, hb0);
            k_headsum<<<dim3(D_ / 256, S_ / 256, AG), 512, 0, stream>>>(
                att, wot, bo, asum, hb0, hb0 != 0);
        }
        k_ln<<<S_, 256, 0, stream>>>(qin + (size_t)b * S_ * D_, asum, gamma, beta,
                                     out + (size_t)b * S_ * D_, AG);
    }
}

// Round 8
// 1201.525 us; speedup vs baseline: 2.3762x; 1.1570x over previous
//
#include <hip/hip_runtime.h>
#include <stdint.h>

#define B_ 4
#define S_ 2048
#define D_ 1024
#define H_ 16
#define A_ 64
#define LN_EPS 1e-3f
#define L2E 1.4426950408889634f

typedef __bf16 bf16x8 __attribute__((ext_vector_type(8)));
typedef __bf16 bf16x4 __attribute__((ext_vector_type(4)));
typedef float f32x4 __attribute__((ext_vector_type(4)));

__device__ __forceinline__ f32x4 mfma16(bf16x8 a, bf16x8 b, f32x4 c) {
    return __builtin_amdgcn_mfma_f32_16x16x32_bf16(a, b, c, 0, 0, 0);
}
__device__ __forceinline__ void glds16(const void* g, void* l) {
    __builtin_amdgcn_global_load_lds(
        (const __attribute__((address_space(1))) void*)g,
        (__attribute__((address_space(3))) void*)l, 16, 0, 0);
}

// ---- swizzled [128][64] half-tile staging (8-phase cores) ----
#define SWZ(slot, r) ((slot) ^ (((r) & 1) << 2) ^ (((r) >> 1) & 3))
__device__ __forceinline__ void stage_half(const __bf16* __restrict__ src, size_t ld,
                                           __bf16* lhalf, int w, int lane) {
    #pragma unroll
    for (int i = 0; i < 2; ++i) {
        int ch = w * 2 + i;
        int r = ch * 8 + (lane >> 3);
        int sl = SWZ(lane & 7, r);
        glds16(src + (size_t)r * ld + sl * 8, lhalf + ch * 512);
    }
}
__device__ __forceinline__ bf16x8 fragS(const __bf16* h, int r, int ks, int fg) {
    return *(const bf16x8*)(h + r * 64 + SWZ(ks * 4 + fg, r) * 8);
}

// ---- linear [128][32] tile staging (proj 2-phase core), 4 waves ----
__device__ __forceinline__ void glds_tile128(const __bf16* __restrict__ src, size_t ld,
                                             __bf16* lds, int w, int lane) {
    int r = lane >> 2;
    int c = (lane & 3) * 8;
    #pragma unroll
    for (int i = 0; i < 2; ++i) {
        int r0 = (w + i * 4) * 16;
        glds16(src + (size_t)(r0 + r) * ld + c, lds + r0 * 32);
    }
}
template <int NI, int NJ>
__device__ __forceinline__ void mfma_tileL(const __bf16* As, const __bf16* Bs,
                                           int wm, int wn, int fr, int fg,
                                           f32x4 (&acc)[NI][NJ]) {
    bf16x8 af[NI], bv[NJ];
    #pragma unroll
    for (int i = 0; i < NI; ++i)
        af[i] = *(const bf16x8*)(As + (wm + i * 16 + fr) * 32 + fg * 8);
    #pragma unroll
    for (int j = 0; j < NJ; ++j)
        bv[j] = *(const bf16x8*)(Bs + (wn + j * 16 + fr) * 32 + fg * 8);
    #pragma unroll
    for (int i = 0; i < NI; ++i)
        #pragma unroll
        for (int j = 0; j < NJ; ++j)
            acc[i][j] = mfma16(af[i], bv[j], acc[i][j]);
}

// ---------------- tiled transpose + f32->bf16 convert ----------------
__global__ void k_tr_cvt(const float* __restrict__ in, __bf16* __restrict__ out,
                         int R, int C) {
    __shared__ float tile[32][33];
    size_t gbase = (size_t)blockIdx.z * R * C;
    int r0 = blockIdx.y * 32, c0 = blockIdx.x * 32;
    #pragma unroll
    for (int i = threadIdx.y; i < 32; i += 8)
        tile[i][threadIdx.x] = in[gbase + (size_t)(r0 + i) * C + c0 + threadIdx.x];
    __syncthreads();
    #pragma unroll
    for (int i = threadIdx.y; i < 32; i += 8)
        out[gbase + (size_t)(c0 + i) * R + r0 + threadIdx.x] = (__bf16)tile[threadIdx.x][i];
}
// two-source variant (Wq + Wk in one dispatch; z<16 -> src0, else src1)
__global__ void k_tr_cvt2(const float* __restrict__ in0, const float* __restrict__ in1,
                          __bf16* __restrict__ out0, __bf16* __restrict__ out1,
                          int R, int C) {
    __shared__ float tile[32][33];
    int z = blockIdx.z;
    const float* in = (z < H_) ? in0 : in1;
    __bf16* out = (z < H_) ? out0 : out1;
    size_t gbase = (size_t)(z & (H_ - 1)) * R * C;
    int r0 = blockIdx.y * 32, c0 = blockIdx.x * 32;
    #pragma unroll
    for (int i = threadIdx.y; i < 32; i += 8)
        tile[i][threadIdx.x] = in[gbase + (size_t)(r0 + i) * C + c0 + threadIdx.x];
    __syncthreads();
    #pragma unroll
    for (int i = threadIdx.y; i < 32; i += 8)
        out[gbase + (size_t)(c0 + i) * R + r0 + threadIdx.x] = (__bf16)tile[threadIdx.x][i];
}

// ---------------- elementwise f32 -> bf16 (two sources via z) ----------------
__global__ void k_cvt2(const float* __restrict__ in0, const float* __restrict__ in1,
                       __bf16* __restrict__ out0, __bf16* __restrict__ out1, int n8) {
    int i = blockIdx.x * blockDim.x + threadIdx.x;
    if (i >= n8) return;
    const float* in = blockIdx.y ? in1 : in0;
    __bf16* out = blockIdx.y ? out1 : out0;
    const float4* p = (const float4*)(in + (size_t)i * 8);
    float4 f0 = p[0], f1 = p[1];
    __bf16 v[8] = {(__bf16)f0.x, (__bf16)f0.y, (__bf16)f0.z, (__bf16)f0.w,
                   (__bf16)f1.x, (__bf16)f1.y, (__bf16)f1.z, (__bf16)f1.w};
    *(uint4*)(out + (size_t)i * 8) = *(const uint4*)v;
}

// ---------------- Q/K projection: bf16 glds 2-phase dbuf, both in one dispatch ----------------
__global__ __launch_bounds__(256) void k_proj(
    const __bf16* __restrict__ qb, const __bf16* __restrict__ kvb,
    const __bf16* __restrict__ wqt, const __bf16* __restrict__ wkt,
    const float* __restrict__ bq, const float* __restrict__ bk,
    __bf16* __restrict__ qp, __bf16* __restrict__ kp) {
    __shared__ __bf16 As[2][128 * 32];
    __shared__ __bf16 Bs[2][128 * 32];
    int which = blockIdx.z;
    const __bf16* Ab = which ? kvb : qb;
    const __bf16* Bt = which ? wkt : wqt;
    const float* bias = which ? bk : bq;
    float scale = which ? 1.0f : 0.125f;
    __bf16* outp = which ? kp : qp;
    int m0 = blockIdx.y * 128, n0 = blockIdx.x * 128;
    int t = threadIdx.x, lane = t & 63, w = t >> 6;
    int wm = (w >> 1) * 64, wn = (w & 1) * 64;
    int fr = lane & 15, fg = lane >> 4;
    const __bf16* Abase = Ab + (size_t)m0 * D_;
    const __bf16* Bbase = Bt + (size_t)n0 * D_;
    f32x4 acc[4][4] = {};
    glds_tile128(Abase, D_, As[0], w, lane);
    glds_tile128(Bbase, D_, Bs[0], w, lane);
    __syncthreads();
    int cur = 0;
    const int nt = D_ / 32;
    for (int tt = 0; tt < nt; ++tt) {
        if (tt + 1 < nt) {
            glds_tile128(Abase + (tt + 1) * 32, D_, As[cur ^ 1], w, lane);
            glds_tile128(Bbase + (tt + 1) * 32, D_, Bs[cur ^ 1], w, lane);
        }
        mfma_tileL<4, 4>(As[cur], Bs[cur], wm, wn, fr, fg, acc);
        __syncthreads();
        cur ^= 1;
    }
    #pragma unroll
    for (int j = 0; j < 4; ++j) {
        int n = n0 + wn + j * 16 + fr;
        float bv = bias[n];
        #pragma unroll
        for (int i = 0; i < 4; ++i)
            #pragma unroll
            for (int jj = 0; jj < 4; ++jj) {
                int m = m0 + wm + i * 16 + fg * 4 + jj;
                outp[(size_t)m * (H_ * A_) + n] = (__bf16)((acc[i][j][jj] + bv) * scale);
            }
    }
}

// ---------------- fused flash attention: QK^T -> exp -> PV, staged, paired ----------------
// 2 barriers per K-tile: K+V(t+1) issued together at phase-A, single vmcnt(5).
__global__ __launch_bounds__(512) void k_fattn(
    const __bf16* __restrict__ qpb, const __bf16* __restrict__ kpb,
    const __bf16* __restrict__ kvtb, __bf16* __restrict__ att, int hb0) {
    __shared__ __bf16 Ks[2][64 * 64];
    __shared__ __bf16 Vs[2][2][128 * 64];
    __shared__ __bf16 Ps[128 * 64];
    __shared__ float lpar[128][2];
    int hl = blockIdx.z;
    int h = hb0 + hl;
    int yp = blockIdx.y;
    int n0 = blockIdx.x * 256;
    int t = threadIdx.x, lane = t & 63, w = t >> 6;
    int fr = lane & 15, fg = lane >> 4;
    int wr = w >> 2, wc = w & 3;   // PV role
    int sr = w >> 1, sc = w & 1;   // QK^T role
    const __bf16* Vb = kvtb + (size_t)n0 * S_;
    __bf16* ob = att + (size_t)hl * S_ * D_;

    #pragma unroll 1
    for (int seg = 0; seg < 2; ++seg) {
        int mt = seg ? (15 - yp) : yp;
        int m0 = mt * 128;
        int NT = (mt + 1) * 2;
        // ---- prologue: Q -> Ps -> regs; K0; V0 ----
        stage_half(qpb + (size_t)m0 * (H_ * A_) + h * A_, H_ * A_, Ps, w, lane);
        {
            int r = w * 8 + (lane >> 3);
            glds16(kpb + (size_t)r * (H_ * A_) + h * A_ + SWZ(lane & 7, r) * 8,
                   &Ks[0][w * 512]);
        }
        asm volatile("s_waitcnt vmcnt(0)" ::: "memory");
        __builtin_amdgcn_s_barrier();
        bf16x8 qf[2][2];
        #pragma unroll
        for (int mi = 0; mi < 2; ++mi)
            #pragma unroll
            for (int ks = 0; ks < 2; ++ks)
                qf[mi][ks] = fragS(Ps, sr * 32 + mi * 16 + fr, ks, fg);
        asm volatile("s_waitcnt lgkmcnt(0)" ::: "memory");
        stage_half(Vb, S_, &Vs[0][0][0], w, lane);
        stage_half(Vb + (size_t)128 * S_, S_, &Vs[0][1][0], w, lane);
        __builtin_amdgcn_s_barrier();  // Q reads done before P~ writes
        __builtin_amdgcn_sched_barrier(0);
        f32x4 acc[4][4] = {};
        float lsum[2][4] = {};
        int cur = 0;
        for (int tt = 0; tt < NT; ++tt) {
            bool pre = (tt + 1 < NT);
            // ---- phase A: issue K+V(t+1); QK^T + exp + P~ store ----
            if (pre) {
                int r = w * 8 + (lane >> 3);
                glds16(kpb + (size_t)((tt + 1) * 64 + r) * (H_ * A_) + h * A_ +
                           SWZ(lane & 7, r) * 8,
                       &Ks[cur ^ 1][w * 512]);
                stage_half(Vb + (tt + 1) * 64, S_, &Vs[cur ^ 1][0][0], w, lane);
                stage_half(Vb + (size_t)128 * S_ + (tt + 1) * 64, S_,
                           &Vs[cur ^ 1][1][0], w, lane);
                asm volatile("s_waitcnt vmcnt(5)" ::: "memory");
            } else {
                asm volatile("s_waitcnt vmcnt(0)" ::: "memory");
            }
            __builtin_amdgcn_s_barrier();
            __builtin_amdgcn_sched_barrier(0);
            f32x4 sac[2][2] = {};
            __builtin_amdgcn_s_setprio(1);
            #pragma unroll
            for (int ks = 0; ks < 2; ++ks)
                #pragma unroll
                for (int nj = 0; nj < 2; ++nj) {
                    bf16x8 kf = fragS(&Ks[cur][0], sc * 32 + nj * 16 + fr, ks, fg);
                    #pragma unroll
                    for (int mi = 0; mi < 2; ++mi)
                        sac[mi][nj] = mfma16(qf[mi][ks], kf, sac[mi][nj]);
                }
            __builtin_amdgcn_s_setprio(0);
            bool dg = (tt >= 2 * mt);
            #pragma unroll
            for (int mi = 0; mi < 2; ++mi)
                #pragma unroll
                for (int nj = 0; nj < 2; ++nj)
                    #pragma unroll
                    for (int jj = 0; jj < 4; ++jj) {
                        int srow = sr * 32 + mi * 16 + fg * 4 + jj;
                        int col = sc * 32 + nj * 16 + fr;
                        float p = exp2f(sac[mi][nj][jj] * L2E);
                        if (dg && (tt * 64 + col > m0 + srow)) p = 0.f;
                        lsum[mi][jj] += p;
                        Ps[srow * 64 + (col ^ (fg << 4))] = (__bf16)p;
                    }
            asm volatile("s_waitcnt lgkmcnt(0)" ::: "memory");
            __builtin_amdgcn_s_barrier();
            __builtin_amdgcn_sched_barrier(0);
            // ---- phase B: PV (V(t) already drained at phase-A wait) ----
            __builtin_amdgcn_s_setprio(1);
            const __bf16* Vh = &Vs[cur][wc >> 1][0];
            #pragma unroll
            for (int ks = 0; ks < 2; ++ks) {
                bf16x8 pa[4], vf[4];
                #pragma unroll
                for (int mi = 0; mi < 4; ++mi) {
                    int r = wr * 64 + mi * 16 + fr;
                    int g = (ks * 4 + fg) ^ (((fr >> 2) & 3) << 1);
                    pa[mi] = *(const bf16x8*)(Ps + r * 64 + g * 8);
                }
                #pragma unroll
                for (int nj = 0; nj < 4; ++nj)
                    vf[nj] = fragS(Vh, (wc & 1) * 64 + nj * 16 + fr, ks, fg);
                #pragma unroll
                for (int mi = 0; mi < 4; ++mi)
                    #pragma unroll
                    for (int nj = 0; nj < 4; ++nj)
                        acc[mi][nj] = mfma16(pa[mi], vf[nj], acc[mi][nj]);
            }
            __builtin_amdgcn_s_setprio(0);
            __builtin_amdgcn_sched_barrier(0);
            cur ^= 1;
        }
        // ---- row sums ----
        #pragma unroll
        for (int mi = 0; mi < 2; ++mi)
            #pragma unroll
            for (int jj = 0; jj < 4; ++jj) {
                float v = lsum[mi][jj];
                v += __shfl_xor(v, 1);
                v += __shfl_xor(v, 2);
                v += __shfl_xor(v, 4);
                v += __shfl_xor(v, 8);
                if (fr == 0) lpar[sr * 32 + mi * 16 + fg * 4 + jj][sc] = v;
            }
        asm volatile("s_waitcnt lgkmcnt(0)" ::: "memory");
        __builtin_amdgcn_s_barrier();
        // ---- epilogue ----
        #pragma unroll
        for (int mi = 0; mi < 4; ++mi)
            #pragma unroll
            for (int jj = 0; jj < 4; ++jj) {
                int row = wr * 64 + mi * 16 + fg * 4 + jj;
                float il = 1.f / (lpar[row][0] + lpar[row][1]);
                int m = m0 + row;
                #pragma unroll
                for (int nj = 0; nj < 4; ++nj) {
                    int n = n0 + wc * 64 + nj * 16 + fr;
                    ob[(size_t)m * D_ + n] = (__bf16)(acc[mi][nj][jj] * il);
                }
            }
        __builtin_amdgcn_s_barrier();  // Ps/lpar reuse across segs
    }
}

// ---------------- per-head Wo GEMM + bias + relu -> bf16 partials, 256^2 8-phase ----------------
__global__ __launch_bounds__(512) void k_headsum(
    const __bf16* __restrict__ att, const __bf16* __restrict__ Wot,
    const float* __restrict__ bo, __bf16* __restrict__ asum) {
    __shared__ __bf16 L[2][4][8192];
    int p = blockIdx.z;  // head 0..15
    int mt = blockIdx.y, n0 = blockIdx.x * 256;
    int m0 = mt * 256;
    int t = threadIdx.x, lane = t & 63, w = t >> 6;
    int wr = w >> 2, wc = w & 3;
    int fr = lane & 15, fg = lane >> 4;
    const __bf16* Ab = att + ((size_t)p * S_ + m0) * D_;
    const __bf16* Bb = Wot + ((size_t)p * D_ + n0) * D_;
    float bv4[4];
    #pragma unroll
    for (int j = 0; j < 4; ++j)
        bv4[j] = bo[(size_t)p * D_ + n0 + wc * 64 + j * 16 + fr];
    f32x4 acc[8][4] = {};
    auto stg = [&](int tt, int h, int buf) {
        const __bf16* s = (h < 2) ? (Ab + (size_t)(h * 128) * D_ + tt * 64)
                                  : (Bb + (size_t)((h - 2) * 128) * D_ + tt * 64);
        stage_half(s, D_, &L[buf][h][0], w, lane);
    };
    auto loads = [&](const __bf16* Ah, const __bf16* Bh, int rb0, int mh, int nh,
                     bf16x8 (&af)[4][2], bf16x8 (&bv)[2][2]) {
        #pragma unroll
        for (int i = 0; i < 4; ++i)
            #pragma unroll
            for (int ks = 0; ks < 2; ++ks)
                af[i][ks] = fragS(Ah, mh * 64 + i * 16 + fr, ks, fg);
        #pragma unroll
        for (int j = 0; j < 2; ++j)
            #pragma unroll
            for (int ks = 0; ks < 2; ++ks)
                bv[j][ks] = fragS(Bh, rb0 + nh * 32 + j * 16 + fr, ks, fg);
    };
    stg(0, 0, 0); stg(0, 1, 0); stg(0, 2, 0); stg(0, 3, 0);
    int cur = 0;
    const int nt = D_ / 64;
    for (int tt = 0; tt < nt; ++tt) {
        bool pre = (tt + 1 < nt);
        const __bf16* Ah = &L[cur][wr][0];
        const __bf16* Bh = &L[cur][2 + (wc >> 1)][0];
        int rb0 = (wc & 1) * 64;
        #pragma unroll
        for (int ph = 0; ph < 4; ++ph) {
            const int mh = ph >> 1, nh = ph & 1;
            bf16x8 af[4][2], bv[2][2];
            if (ph == 0) {
                if (pre) {
                    stg(tt + 1, 0, cur ^ 1);
                    stg(tt + 1, 1, cur ^ 1);
                    stg(tt + 1, 2, cur ^ 1);
                    stg(tt + 1, 3, cur ^ 1);
                    asm volatile("s_waitcnt vmcnt(8)" ::: "memory");
                } else {
                    asm volatile("s_waitcnt vmcnt(0)" ::: "memory");
                }
                __builtin_amdgcn_s_barrier();
                __builtin_amdgcn_sched_barrier(0);
                loads(Ah, Bh, rb0, mh, nh, af, bv);
            } else {
                loads(Ah, Bh, rb0, mh, nh, af, bv);
                __builtin_amdgcn_s_barrier();
                __builtin_amdgcn_sched_barrier(0);
            }
            __builtin_amdgcn_s_setprio(1);
            #pragma unroll
            for (int i = 0; i < 4; ++i)
                #pragma unroll
                for (int j = 0; j < 2; ++j) {
                    acc[mh * 4 + i][nh * 2 + j] =
                        mfma16(af[i][0], bv[j][0], acc[mh * 4 + i][nh * 2 + j]);
                    acc[mh * 4 + i][nh * 2 + j] =
                        mfma16(af[i][1], bv[j][1], acc[mh * 4 + i][nh * 2 + j]);
                }
            __builtin_amdgcn_s_setprio(0);
            __builtin_amdgcn_sched_barrier(0);
            __builtin_amdgcn_s_barrier();
        }
        cur ^= 1;
    }
    __bf16* dst = asum + ((size_t)p * S_ + m0) * D_;
    #pragma unroll
    for (int mi = 0; mi < 8; ++mi)
        #pragma unroll
        for (int jj = 0; jj < 4; ++jj) {
            int mr = wr * 128 + mi * 16 + fg * 4 + jj;
            #pragma unroll
            for (int nj = 0; nj < 4; ++nj) {
                int nc = n0 + wc * 64 + nj * 16 + fr;
                dst[(size_t)mr * D_ + nc] = (__bf16)fmaxf(acc[mi][nj][jj] + bv4[nj], 0.f);
            }
        }
}

// ---------------- residual + 16-partial bf16 sum + LayerNorm (per batch) ----------------
__global__ __launch_bounds__(256) void k_ln(
    const float* __restrict__ x1b, const __bf16* __restrict__ parts,
    const float* __restrict__ gamma, const float* __restrict__ beta,
    float* __restrict__ outb) {
    int row = blockIdx.x;
    size_t base = (size_t)row * D_;
    int c = threadIdx.x * 4;
    float4 a = *(const float4*)(x1b + base + c);
    float x[4] = {a.x, a.y, a.z, a.w};
    #pragma unroll
    for (int p = 0; p < H_; ++p) {
        bf16x4 v = *(const bf16x4*)(parts + ((size_t)p * S_ + row) * D_ + c);
        x[0] += (float)v[0]; x[1] += (float)v[1];
        x[2] += (float)v[2]; x[3] += (float)v[3];
    }
    float sm = x[0] + x[1] + x[2] + x[3];
    float s2 = x[0] * x[0] + x[1] * x[1] + x[2] * x[2] + x[3] * x[3];
    #pragma unroll
    for (int m = 32; m >= 1; m >>= 1) {
        sm += __shfl_xor(sm, m);
        s2 += __shfl_xor(s2, m);
    }
    __shared__ float r1[4], r2[4];
    int w = threadIdx.x >> 6;
    if ((threadIdx.x & 63) == 0) { r1[w] = sm; r2[w] = s2; }
    __syncthreads();
    sm = r1[0] + r1[1] + r1[2] + r1[3];
    s2 = r2[0] + r2[1] + r2[2] + r2[3];
    float mean = sm * (1.f / D_);
    float var = s2 * (1.f / D_) - mean * mean;
    float rstd = rsqrtf(var + LN_EPS);
    #pragma unroll
    for (int jj = 0; jj < 4; ++jj)
        outb[base + c + jj] = gamma[c + jj] * (x[jj] - mean) * rstd + beta[c + jj];
}

// ---------------- host ----------------
extern "C" void kernel_launch(void* const* d_in, const int* in_sizes, int n_in,
                              void* d_out, int out_size, void* d_ws, size_t ws_size,
                              hipStream_t stream) {
    (void)in_sizes; (void)n_in; (void)out_size; (void)ws_size;
    const float* qin   = (const float*)d_in[0];
    const float* kvin  = (const float*)d_in[1];
    const float* Wq    = (const float*)d_in[2];
    const float* bq    = (const float*)d_in[3];
    const float* Wk    = (const float*)d_in[4];
    const float* bk    = (const float*)d_in[5];
    const float* Wo    = (const float*)d_in[6];
    const float* bo    = (const float*)d_in[7];
    const float* gamma = (const float*)d_in[8];
    const float* beta  = (const float*)d_in[9];
    float* out = (float*)d_out;
    char* ws = (char*)d_ws;

    size_t off = 0;
    auto alloc = [&](size_t bytes) {
        size_t o = off;
        off += (bytes + 255) & ~(size_t)255;
        return o;
    };
    size_t o_wqt = alloc((size_t)H_ * A_ * D_ * 2);
    size_t o_wkt = alloc((size_t)H_ * A_ * D_ * 2);
    size_t o_wot = alloc((size_t)H_ * D_ * D_ * 2);
    size_t o_kvt = alloc((size_t)B_ * D_ * S_ * 2);
    size_t o_qp  = alloc((size_t)B_ * S_ * H_ * A_ * 2);
    size_t o_kp  = alloc((size_t)B_ * S_ * H_ * A_ * 2);
    size_t o_att = alloc((size_t)H_ * S_ * D_ * 2);
    // region X: qb+kvb (bf16, proj inputs) first, then asum (bf16 partials) — disjoint lifetimes
    size_t xbytes_qb = (size_t)B_ * S_ * D_ * 2 * 2;       // qb + kvb
    size_t xbytes_as = (size_t)H_ * S_ * D_ * 2;           // asum bf16 (per batch)
    size_t o_x = alloc(xbytes_qb > xbytes_as ? xbytes_qb : xbytes_as);

    __bf16* wqt = (__bf16*)(ws + o_wqt);
    __bf16* wkt = (__bf16*)(ws + o_wkt);
    __bf16* wot = (__bf16*)(ws + o_wot);
    __bf16* kvt = (__bf16*)(ws + o_kvt);
    __bf16* qp  = (__bf16*)(ws + o_qp);
    __bf16* kp  = (__bf16*)(ws + o_kp);
    __bf16* att = (__bf16*)(ws + o_att);
    __bf16* qb  = (__bf16*)(ws + o_x);
    __bf16* kvb = qb + (size_t)B_ * S_ * D_;
    __bf16* asum = (__bf16*)(ws + o_x);

    // weight transposes + activation converts
    k_tr_cvt2<<<dim3(A_ / 32, D_ / 32, 2 * H_), dim3(32, 8), 0, stream>>>(
        Wq, Wk, wqt, wkt, D_, A_);
    k_tr_cvt<<<dim3(D_ / 32, D_ / 32, H_), dim3(32, 8), 0, stream>>>(Wo, wot, D_, D_);
    k_tr_cvt<<<dim3(D_ / 32, S_ / 32, B_), dim3(32, 8), 0, stream>>>(kvin, kvt, S_, D_);
    int n8 = B_ * S_ * D_ / 8;
    k_cvt2<<<dim3((n8 + 255) / 256, 2), 256, 0, stream>>>(qin, kvin, qb, kvb, n8);
    // both projections in one dispatch (q pre-scaled by 1/sqrt(A))
    k_proj<<<dim3(8, 64, 2), 256, 0, stream>>>(qb, kvb, wqt, wkt, bq, bk, qp, kp);

    for (int b = 0; b < B_; ++b) {
        const __bf16* qpb  = qp + (size_t)b * S_ * (H_ * A_);
        const __bf16* kpb  = kp + (size_t)b * S_ * (H_ * A_);
        const __bf16* kvtb = kvt + (size_t)b * D_ * S_;
        k_fattn<<<dim3(D_ / 256, 8, H_), 512, 0, stream>>>(qpb, kpb, kvtb, att, 0);
        k_headsum<<<dim3(D_ / 256, S_ / 256, H_), 512, 0, stream>>>(att, wot, bo, asum);
        k_ln<<<S_, 256, 0, stream>>>(qin + (size_t)b * S_ * D_, asum, gamma, beta,
                                     out + (size_t)b * S_ * D_);
    }
}

// Round 10
// 1143.154 us; speedup vs baseline: 2.4975x; 1.0511x over previous
//
#include <hip/hip_runtime.h>
#include <stdint.h>

#define B_ 4
#define S_ 2048
#define D_ 1024
#define H_ 16
#define A_ 64
#define LN_EPS 1e-3f
#define L2E 1.4426950408889634f

typedef __bf16 bf16x8 __attribute__((ext_vector_type(8)));
typedef __bf16 bf16x4 __attribute__((ext_vector_type(4)));
typedef float f32x4 __attribute__((ext_vector_type(4)));

__device__ __forceinline__ f32x4 mfma16(bf16x8 a, bf16x8 b, f32x4 c) {
    return __builtin_amdgcn_mfma_f32_16x16x32_bf16(a, b, c, 0, 0, 0);
}
__device__ __forceinline__ void glds16(const void* g, void* l) {
    __builtin_amdgcn_global_load_lds(
        (const __attribute__((address_space(1))) void*)g,
        (__attribute__((address_space(3))) void*)l, 16, 0, 0);
}

// ---- swizzled [128][64] half-tile staging ----
#define SWZ(slot, r) ((slot) ^ (((r) & 1) << 2) ^ (((r) >> 1) & 3))
__device__ __forceinline__ void stage_half(const __bf16* __restrict__ src, size_t ld,
                                           __bf16* lhalf, int w, int lane) {
    #pragma unroll
    for (int i = 0; i < 2; ++i) {
        int ch = w * 2 + i;
        int r = ch * 8 + (lane >> 3);
        int sl = SWZ(lane & 7, r);
        glds16(src + (size_t)r * ld + sl * 8, lhalf + ch * 512);
    }
}
__device__ __forceinline__ bf16x8 fragS(const __bf16* h, int r, int ks, int fg) {
    return *(const bf16x8*)(h + r * 64 + SWZ(ks * 4 + fg, r) * 8);
}

// ---- linear [128][32] tile staging (proj 2-phase core), 4 waves ----
__device__ __forceinline__ void glds_tile128(const __bf16* __restrict__ src, size_t ld,
                                             __bf16* lds, int w, int lane) {
    int r = lane >> 2;
    int c = (lane & 3) * 8;
    #pragma unroll
    for (int i = 0; i < 2; ++i) {
        int r0 = (w + i * 4) * 16;
        glds16(src + (size_t)(r0 + r) * ld + c, lds + r0 * 32);
    }
}
template <int NI, int NJ>
__device__ __forceinline__ void mfma_tileL(const __bf16* As, const __bf16* Bs,
                                           int wm, int wn, int fr, int fg,
                                           f32x4 (&acc)[NI][NJ]) {
    bf16x8 af[NI], bv[NJ];
    #pragma unroll
    for (int i = 0; i < NI; ++i)
        af[i] = *(const bf16x8*)(As + (wm + i * 16 + fr) * 32 + fg * 8);
    #pragma unroll
    for (int j = 0; j < NJ; ++j)
        bv[j] = *(const bf16x8*)(Bs + (wn + j * 16 + fr) * 32 + fg * 8);
    #pragma unroll
    for (int i = 0; i < NI; ++i)
        #pragma unroll
        for (int j = 0; j < NJ; ++j)
            acc[i][j] = mfma16(af[i], bv[j], acc[i][j]);
}

// ---------------- tiled transpose + f32->bf16 convert ----------------
__global__ void k_tr_cvt(const float* __restrict__ in, __bf16* __restrict__ out,
                         int R, int C) {
    __shared__ float tile[32][33];
    size_t gbase = (size_t)blockIdx.z * R * C;
    int r0 = blockIdx.y * 32, c0 = blockIdx.x * 32;
    #pragma unroll
    for (int i = threadIdx.y; i < 32; i += 8)
        tile[i][threadIdx.x] = in[gbase + (size_t)(r0 + i) * C + c0 + threadIdx.x];
    __syncthreads();
    #pragma unroll
    for (int i = threadIdx.y; i < 32; i += 8)
        out[gbase + (size_t)(c0 + i) * R + r0 + threadIdx.x] = (__bf16)tile[threadIdx.x][i];
}
__global__ void k_tr_cvt2(const float* __restrict__ in0, const float* __restrict__ in1,
                          __bf16* __restrict__ out0, __bf16* __restrict__ out1,
                          int R, int C) {
    __shared__ float tile[32][33];
    int z = blockIdx.z;
    const float* in = (z < H_) ? in0 : in1;
    __bf16* out = (z < H_) ? out0 : out1;
    size_t gbase = (size_t)(z & (H_ - 1)) * R * C;
    int r0 = blockIdx.y * 32, c0 = blockIdx.x * 32;
    #pragma unroll
    for (int i = threadIdx.y; i < 32; i += 8)
        tile[i][threadIdx.x] = in[gbase + (size_t)(r0 + i) * C + c0 + threadIdx.x];
    __syncthreads();
    #pragma unroll
    for (int i = threadIdx.y; i < 32; i += 8)
        out[gbase + (size_t)(c0 + i) * R + r0 + threadIdx.x] = (__bf16)tile[threadIdx.x][i];
}

// ---------------- elementwise f32 -> bf16 (two sources via z) ----------------
__global__ void k_cvt2(const float* __restrict__ in0, const float* __restrict__ in1,
                       __bf16* __restrict__ out0, __bf16* __restrict__ out1, int n8) {
    int i = blockIdx.x * blockDim.x + threadIdx.x;
    if (i >= n8) return;
    const float* in = blockIdx.y ? in1 : in0;
    __bf16* out = blockIdx.y ? out1 : out0;
    const float4* p = (const float4*)(in + (size_t)i * 8);
    float4 f0 = p[0], f1 = p[1];
    __bf16 v[8] = {(__bf16)f0.x, (__bf16)f0.y, (__bf16)f0.z, (__bf16)f0.w,
                   (__bf16)f1.x, (__bf16)f1.y, (__bf16)f1.z, (__bf16)f1.w};
    *(uint4*)(out + (size_t)i * 8) = *(const uint4*)v;
}

// ---------------- Q/K projection: bf16 glds 2-phase dbuf, both in one dispatch ----------------
__global__ __launch_bounds__(256) void k_proj(
    const __bf16* __restrict__ qb, const __bf16* __restrict__ kvb,
    const __bf16* __restrict__ wqt, const __bf16* __restrict__ wkt,
    const float* __restrict__ bq, const float* __restrict__ bk,
    __bf16* __restrict__ qp, __bf16* __restrict__ kp) {
    __shared__ __bf16 As[2][128 * 32];
    __shared__ __bf16 Bs[2][128 * 32];
    int which = blockIdx.z;
    const __bf16* Ab = which ? kvb : qb;
    const __bf16* Bt = which ? wkt : wqt;
    const float* bias = which ? bk : bq;
    float scale = which ? 1.0f : 0.125f;
    __bf16* outp = which ? kp : qp;
    int m0 = blockIdx.y * 128, n0 = blockIdx.x * 128;
    int t = threadIdx.x, lane = t & 63, w = t >> 6;
    int wm = (w >> 1) * 64, wn = (w & 1) * 64;
    int fr = lane & 15, fg = lane >> 4;
    const __bf16* Abase = Ab + (size_t)m0 * D_;
    const __bf16* Bbase = Bt + (size_t)n0 * D_;
    f32x4 acc[4][4] = {};
    glds_tile128(Abase, D_, As[0], w, lane);
    glds_tile128(Bbase, D_, Bs[0], w, lane);
    __syncthreads();
    int cur = 0;
    const int nt = D_ / 32;
    for (int tt = 0; tt < nt; ++tt) {
        if (tt + 1 < nt) {
            glds_tile128(Abase + (tt + 1) * 32, D_, As[cur ^ 1], w, lane);
            glds_tile128(Bbase + (tt + 1) * 32, D_, Bs[cur ^ 1], w, lane);
        }
        mfma_tileL<4, 4>(As[cur], Bs[cur], wm, wn, fr, fg, acc);
        __syncthreads();
        cur ^= 1;
    }
    #pragma unroll
    for (int j = 0; j < 4; ++j) {
        int n = n0 + wn + j * 16 + fr;
        float bv = bias[n];
        #pragma unroll
        for (int i = 0; i < 4; ++i)
            #pragma unroll
            for (int jj = 0; jj < 4; ++jj) {
                int m = m0 + wm + i * 16 + fg * 4 + jj;
                outp[(size_t)m * (H_ * A_) + n] = (__bf16)((acc[i][j][jj] + bv) * scale);
            }
    }
}

// ---------------- fused flash attention, BN=512, race-free ledger ----------------
// block (n0/512, yp, h): segments mt=yp and mt=15-yp (uniform 34 K-tiles of 64).
// Q[128][64] in regs; K single-buf LDS + reg prefetch; V [512][64] dbuf glds.
// RACE FIX vs R9: V(t+1) staging is issued in PHASE B after the post-P~ barrier,
// so all waves have drained their PV(t-1) reads of Vs[cur^1] (phase-A lgkm+barrier)
// before any glds write can land there — safe by construction, not by timing.
// Ledger: entering phase A: [V(t)x8, kreg(t+1)] -> vmcnt(1) drains V(t).
// Phase B: issue V(t+1)x8; vmcnt(8) drains kreg(t+1); Ks<-kreg; load kreg(t+2).
__global__ __launch_bounds__(512, 1) void k_fattn(
    const __bf16* __restrict__ qpb, const __bf16* __restrict__ kpb,
    const __bf16* __restrict__ kvtb, __bf16* __restrict__ att) {
    __shared__ __bf16 Ks[64 * 64];          // 8 KB, single buffer
    __shared__ __bf16 Vs[2][4][128 * 64];   // 128 KB
    __shared__ __bf16 Ps[128 * 64];         // 16 KB (also Q staging)
    __shared__ float lpar[128][2];          // 1 KB
    int h = blockIdx.z;
    int yp = blockIdx.y;
    int n0 = blockIdx.x * 512;
    int t = threadIdx.x, lane = t & 63, w = t >> 6;
    int fr = lane & 15, fg = lane >> 4;
    int wr = w >> 2, wc = w & 3;   // PV: rows wr*64, cols wc*128
    int sr = w >> 1, sc = w & 1;   // QK^T: rows sr*32, cols sc*32
    const __bf16* Vb = kvtb + (size_t)n0 * S_;
    __bf16* ob = att + (size_t)h * S_ * D_;
    int kr = w * 8 + (lane >> 3);       // K stage row (64 rows over 8 waves)
    int ksl = SWZ(lane & 7, kr);        // K stage source slot

    #pragma unroll 1
    for (int seg = 0; seg < 2; ++seg) {
        int mt = seg ? (15 - yp) : yp;
        int m0 = mt * 128;
        int NT = (mt + 1) * 2;
        // ---- prologue: Q -> Ps -> regs; K0 glds; V0 glds; K1 -> reg ----
        stage_half(qpb + (size_t)m0 * (H_ * A_) + h * A_, H_ * A_, Ps, w, lane);
        glds16(kpb + (size_t)kr * (H_ * A_) + h * A_ + ksl * 8, Ks + w * 512);
        asm volatile("s_waitcnt vmcnt(0)" ::: "memory");
        __builtin_amdgcn_s_barrier();
        bf16x8 qf[2][2];
        #pragma unroll
        for (int mi = 0; mi < 2; ++mi)
            #pragma unroll
            for (int ks = 0; ks < 2; ++ks)
                qf[mi][ks] = fragS(Ps, sr * 32 + mi * 16 + fr, ks, fg);
        asm volatile("s_waitcnt lgkmcnt(0)" ::: "memory");
        #pragma unroll
        for (int q = 0; q < 4; ++q)
            stage_half(Vb + (size_t)(q * 128) * S_, S_, &Vs[0][q][0], w, lane);
        uint4 kreg = {0, 0, 0, 0};
        if (NT > 1)
            kreg = *(const uint4*)(kpb + (size_t)(64 + kr) * (H_ * A_) + h * A_ + ksl * 8);
        __builtin_amdgcn_s_barrier();  // Q reads done before P~ writes
        __builtin_amdgcn_sched_barrier(0);
        f32x4 acc[4][8] = {};
        float lsum[2][4] = {};
        int cur = 0;
        for (int tt = 0; tt < NT; ++tt) {
            bool pre = (tt + 1 < NT);
            // ---- phase A: wait V(t); QK^T + exp + P~ store ----
            if (pre) {
                asm volatile("s_waitcnt vmcnt(1)" ::: "memory");   // drain V(t)x8
            } else {
                asm volatile("s_waitcnt vmcnt(0)" ::: "memory");
            }
            asm volatile("s_waitcnt lgkmcnt(0)" ::: "memory");
            __builtin_amdgcn_s_barrier();
            __builtin_amdgcn_sched_barrier(0);
            f32x4 sac[2][2] = {};
            __builtin_amdgcn_s_setprio(1);
            #pragma unroll
            for (int ks = 0; ks < 2; ++ks)
                #pragma unroll
                for (int nj = 0; nj < 2; ++nj) {
                    bf16x8 kf = fragS(Ks, sc * 32 + nj * 16 + fr, ks, fg);
                    #pragma unroll
                    for (int mi = 0; mi < 2; ++mi)
                        sac[mi][nj] = mfma16(qf[mi][ks], kf, sac[mi][nj]);
                }
            __builtin_amdgcn_s_setprio(0);
            bool dg = (tt >= 2 * mt);
            #pragma unroll
            for (int mi = 0; mi < 2; ++mi)
                #pragma unroll
                for (int nj = 0; nj < 2; ++nj)
                    #pragma unroll
                    for (int jj = 0; jj < 4; ++jj) {
                        int srow = sr * 32 + mi * 16 + fg * 4 + jj;
                        int col = sc * 32 + nj * 16 + fr;
                        float p = exp2f(sac[mi][nj][jj] * L2E);
                        if (dg && (tt * 64 + col > m0 + srow)) p = 0.f;
                        lsum[mi][jj] += p;
                        Ps[srow * 64 + (col ^ (fg << 4))] = (__bf16)p;
                    }
            asm volatile("s_waitcnt lgkmcnt(0)" ::: "memory");
            __builtin_amdgcn_s_barrier();
            __builtin_amdgcn_sched_barrier(0);
            // ---- phase B: issue V(t+1) (safe now); K(t+1) reg->LDS; PV ----
            if (pre) {
                #pragma unroll
                for (int q = 0; q < 4; ++q)
                    stage_half(Vb + (size_t)(q * 128) * S_ + (tt + 1) * 64, S_,
                               &Vs[cur ^ 1][q][0], w, lane);
                asm volatile("s_waitcnt vmcnt(8)" ::: "memory");   // drain kreg(t+1)
                *(uint4*)(Ks + w * 512 + lane * 8) = kreg;
                if (tt + 2 < NT)
                    kreg = *(const uint4*)(kpb + (size_t)((tt + 2) * 64 + kr) * (H_ * A_) +
                                           h * A_ + ksl * 8);
            }
            __builtin_amdgcn_s_setprio(1);
            const __bf16* Vh = &Vs[cur][wc][0];
            #pragma unroll
            for (int ks = 0; ks < 2; ++ks) {
                bf16x8 pa[4], vf[8];
                #pragma unroll
                for (int mi = 0; mi < 4; ++mi) {
                    int r = wr * 64 + mi * 16 + fr;
                    int g = (ks * 4 + fg) ^ (((fr >> 2) & 3) << 1);
                    pa[mi] = *(const bf16x8*)(Ps + r * 64 + g * 8);
                }
                #pragma unroll
                for (int nj = 0; nj < 8; ++nj)
                    vf[nj] = fragS(Vh, nj * 16 + fr, ks, fg);
                #pragma unroll
                for (int mi = 0; mi < 4; ++mi)
                    #pragma unroll
                    for (int nj = 0; nj < 8; ++nj)
                        acc[mi][nj] = mfma16(pa[mi], vf[nj], acc[mi][nj]);
            }
            __builtin_amdgcn_s_setprio(0);
            __builtin_amdgcn_sched_barrier(0);
            cur ^= 1;
        }
        // ---- row sums: shfl over fr, combine the 2 col-waves via LDS ----
        #pragma unroll
        for (int mi = 0; mi < 2; ++mi)
            #pragma unroll
            for (int jj = 0; jj < 4; ++jj) {
                float v = lsum[mi][jj];
                v += __shfl_xor(v, 1);
                v += __shfl_xor(v, 2);
                v += __shfl_xor(v, 4);
                v += __shfl_xor(v, 8);
                if (fr == 0) lpar[sr * 32 + mi * 16 + fg * 4 + jj][sc] = v;
            }
        asm volatile("s_waitcnt lgkmcnt(0)" ::: "memory");
        __builtin_amdgcn_s_barrier();
        // ---- epilogue: normalize + store ----
        #pragma unroll
        for (int mi = 0; mi < 4; ++mi)
            #pragma unroll
            for (int jj = 0; jj < 4; ++jj) {
                int row = wr * 64 + mi * 16 + fg * 4 + jj;
                float il = 1.f / (lpar[row][0] + lpar[row][1]);
                int m = m0 + row;
                #pragma unroll
                for (int nj = 0; nj < 8; ++nj) {
                    int n = n0 + wc * 128 + nj * 16 + fr;
                    ob[(size_t)m * D_ + n] = (__bf16)(acc[mi][nj][jj] * il);
                }
            }
        __builtin_amdgcn_s_barrier();  // Ps/lpar/Ks reuse across segs
    }
}

// ---------------- per-head Wo GEMM + bias + relu -> bf16 partials, 256^2 8-phase ----------------
__global__ __launch_bounds__(512) void k_headsum(
    const __bf16* __restrict__ att, const __bf16* __restrict__ Wot,
    const float* __restrict__ bo, __bf16* __restrict__ asum) {
    __shared__ __bf16 L[2][4][8192];
    int p = blockIdx.z;  // head 0..15
    int mt = blockIdx.y, n0 = blockIdx.x * 256;
    int m0 = mt * 256;
    int t = threadIdx.x, lane = t & 63, w = t >> 6;
    int wr = w >> 2, wc = w & 3;
    int fr = lane & 15, fg = lane >> 4;
    const __bf16* Ab = att + ((size_t)p * S_ + m0) * D_;
    const __bf16* Bb = Wot + ((size_t)p * D_ + n0) * D_;
    float bv4[4];
    #pragma unroll
    for (int j = 0; j < 4; ++j)
        bv4[j] = bo[(size_t)p * D_ + n0 + wc * 64 + j * 16 + fr];
    f32x4 acc[8][4] = {};
    auto stg = [&](int tt, int h, int buf) {
        const __bf16* s = (h < 2) ? (Ab + (size_t)(h * 128) * D_ + tt * 64)
                                  : (Bb + (size_t)((h - 2) * 128) * D_ + tt * 64);
        stage_half(s, D_, &L[buf][h][0], w, lane);
    };
    auto loads = [&](const __bf16* Ah, const __bf16* Bh, int rb0, int mh, int nh,
                     bf16x8 (&af)[4][2], bf16x8 (&bv)[2][2]) {
        #pragma unroll
        for (int i = 0; i < 4; ++i)
            #pragma unroll
            for (int ks = 0; ks < 2; ++ks)
                af[i][ks] = fragS(Ah, mh * 64 + i * 16 + fr, ks, fg);
        #pragma unroll
        for (int j = 0; j < 2; ++j)
            #pragma unroll
            for (int ks = 0; ks < 2; ++ks)
                bv[j][ks] = fragS(Bh, rb0 + nh * 32 + j * 16 + fr, ks, fg);
    };
    stg(0, 0, 0); stg(0, 1, 0); stg(0, 2, 0); stg(0, 3, 0);
    int cur = 0;
    const int nt = D_ / 64;
    for (int tt = 0; tt < nt; ++tt) {
        bool pre = (tt + 1 < nt);
        const __bf16* Ah = &L[cur][wr][0];
        const __bf16* Bh = &L[cur][2 + (wc >> 1)][0];
        int rb0 = (wc & 1) * 64;
        #pragma unroll
        for (int ph = 0; ph < 4; ++ph) {
            const int mh = ph >> 1, nh = ph & 1;
            bf16x8 af[4][2], bv[2][2];
            if (ph == 0) {
                if (pre) {
                    stg(tt + 1, 0, cur ^ 1);
                    stg(tt + 1, 1, cur ^ 1);
                    stg(tt + 1, 2, cur ^ 1);
                    stg(tt + 1, 3, cur ^ 1);
                    asm volatile("s_waitcnt vmcnt(8)" ::: "memory");
                } else {
                    asm volatile("s_waitcnt vmcnt(0)" ::: "memory");
                }
                __builtin_amdgcn_s_barrier();
                __builtin_amdgcn_sched_barrier(0);
                loads(Ah, Bh, rb0, mh, nh, af, bv);
            } else {
                loads(Ah, Bh, rb0, mh, nh, af, bv);
                __builtin_amdgcn_s_barrier();
                __builtin_amdgcn_sched_barrier(0);
            }
            __builtin_amdgcn_s_setprio(1);
            #pragma unroll
            for (int i = 0; i < 4; ++i)
                #pragma unroll
                for (int j = 0; j < 2; ++j) {
                    acc[mh * 4 + i][nh * 2 + j] =
                        mfma16(af[i][0], bv[j][0], acc[mh * 4 + i][nh * 2 + j]);
                    acc[mh * 4 + i][nh * 2 + j] =
                        mfma16(af[i][1], bv[j][1], acc[mh * 4 + i][nh * 2 + j]);
                }
            __builtin_amdgcn_s_setprio(0);
            __builtin_amdgcn_sched_barrier(0);
            __builtin_amdgcn_s_barrier();
        }
        cur ^= 1;
    }
    __bf16* dst = asum + ((size_t)p * S_ + m0) * D_;
    #pragma unroll
    for (int mi = 0; mi < 8; ++mi)
        #pragma unroll
        for (int jj = 0; jj < 4; ++jj) {
            int mr = wr * 128 + mi * 16 + fg * 4 + jj;
            #pragma unroll
            for (int nj = 0; nj < 4; ++nj) {
                int nc = n0 + wc * 64 + nj * 16 + fr;
                dst[(size_t)mr * D_ + nc] = (__bf16)fmaxf(acc[mi][nj][jj] + bv4[nj], 0.f);
            }
        }
}

// ---------------- residual + 16-partial bf16 sum + LayerNorm (per batch) ----------------
__global__ __launch_bounds__(256) void k_ln(
    const float* __restrict__ x1b, const __bf16* __restrict__ parts,
    const float* __restrict__ gamma, const float* __restrict__ beta,
    float* __restrict__ outb) {
    int row = blockIdx.x;
    size_t base = (size_t)row * D_;
    int c = threadIdx.x * 4;
    float4 a = *(const float4*)(x1b + base + c);
    float x[4] = {a.x, a.y, a.z, a.w};
    #pragma unroll
    for (int p = 0; p < H_; ++p) {
        bf16x4 v = *(const bf16x4*)(parts + ((size_t)p * S_ + row) * D_ + c);
        x[0] += (float)v[0]; x[1] += (float)v[1];
        x[2] += (float)v[2]; x[3] += (float)v[3];
    }
    float sm = x[0] + x[1] + x[2] + x[3];
    float s2 = x[0] * x[0] + x[1] * x[1] + x[2] * x[2] + x[3] * x[3];
    #pragma unroll
    for (int m = 32; m >= 1; m >>= 1) {
        sm += __shfl_xor(sm, m);
        s2 += __shfl_xor(s2, m);
    }
    __shared__ float r1[4], r2[4];
    int w = threadIdx.x >> 6;
    if ((threadIdx.x & 63) == 0) { r1[w] = sm; r2[w] = s2; }
    __syncthreads();
    sm = r1[0] + r1[1] + r1[2] + r1[3];
    s2 = r2[0] + r2[1] + r2[2] + r2[3];
    float mean = sm * (1.f / D_);
    float var = s2 * (1.f / D_) - mean * mean;
    float rstd = rsqrtf(var + LN_EPS);
    #pragma unroll
    for (int jj = 0; jj < 4; ++jj)
        outb[base + c + jj] = gamma[c + jj] * (x[jj] - mean) * rstd + beta[c + jj];
}

// ---------------- host ----------------
extern "C" void kernel_launch(void* const* d_in, const int* in_sizes, int n_in,
                              void* d_out, int out_size, void* d_ws, size_t ws_size,
                              hipStream_t stream) {
    (void)in_sizes; (void)n_in; (void)out_size; (void)ws_size;
    const float* qin   = (const float*)d_in[0];
    const float* kvin  = (const float*)d_in[1];
    const float* Wq    = (const float*)d_in[2];
    const float* bq    = (const float*)d_in[3];
    const float* Wk    = (const float*)d_in[4];
    const float* bk    = (const float*)d_in[5];
    const float* Wo    = (const float*)d_in[6];
    const float* bo    = (const float*)d_in[7];
    const float* gamma = (const float*)d_in[8];
    const float* beta  = (const float*)d_in[9];
    float* out = (float*)d_out;
    char* ws = (char*)d_ws;

    size_t off = 0;
    auto alloc = [&](size_t bytes) {
        size_t o = off;
        off += (bytes + 255) & ~(size_t)255;
        return o;
    };
    size_t o_wqt = alloc((size_t)H_ * A_ * D_ * 2);
    size_t o_wkt = alloc((size_t)H_ * A_ * D_ * 2);
    size_t o_wot = alloc((size_t)H_ * D_ * D_ * 2);
    size_t o_kvt = alloc((size_t)B_ * D_ * S_ * 2);
    size_t o_qp  = alloc((size_t)B_ * S_ * H_ * A_ * 2);
    size_t o_kp  = alloc((size_t)B_ * S_ * H_ * A_ * 2);
    size_t o_att = alloc((size_t)H_ * S_ * D_ * 2);
    // region X: qb+kvb (proj inputs) then asum (bf16 partials) — disjoint lifetimes
    size_t xbytes_qb = (size_t)B_ * S_ * D_ * 2 * 2;
    size_t xbytes_as = (size_t)H_ * S_ * D_ * 2;
    size_t o_x = alloc(xbytes_qb > xbytes_as ? xbytes_qb : xbytes_as);

    __bf16* wqt = (__bf16*)(ws + o_wqt);
    __bf16* wkt = (__bf16*)(ws + o_wkt);
    __bf16* wot = (__bf16*)(ws + o_wot);
    __bf16* kvt = (__bf16*)(ws + o_kvt);
    __bf16* qp  = (__bf16*)(ws + o_qp);
    __bf16* kp  = (__bf16*)(ws + o_kp);
    __bf16* att = (__bf16*)(ws + o_att);
    __bf16* qb  = (__bf16*)(ws + o_x);
    __bf16* kvb = qb + (size_t)B_ * S_ * D_;
    __bf16* asum = (__bf16*)(ws + o_x);

    k_tr_cvt2<<<dim3(A_ / 32, D_ / 32, 2 * H_), dim3(32, 8), 0, stream>>>(
        Wq, Wk, wqt, wkt, D_, A_);
    k_tr_cvt<<<dim3(D_ / 32, D_ / 32, H_), dim3(32, 8), 0, stream>>>(Wo, wot, D_, D_);
    k_tr_cvt<<<dim3(D_ / 32, S_ / 32, B_), dim3(32, 8), 0, stream>>>(kvin, kvt, S_, D_);
    int n8 = B_ * S_ * D_ / 8;
    k_cvt2<<<dim3((n8 + 255) / 256, 2), 256, 0, stream>>>(qin, kvin, qb, kvb, n8);
    k_proj<<<dim3(8, 64, 2), 256, 0, stream>>>(qb, kvb, wqt, wkt, bq, bk, qp, kp);

    for (int b = 0; b < B_; ++b) {
        const __bf16* qpb  = qp + (size_t)b * S_ * (H_ * A_);
        const __bf16* kpb  = kp + (size_t)b * S_ * (H_ * A_);
        const __bf16* kvtb = kvt + (size_t)b * D_ * S_;
        k_fattn<<<dim3(D_ / 512, 8, H_), 512, 0, stream>>>(qpb, kpb, kvtb, att);
        k_headsum<<<dim3(D_ / 256, S_ / 256, H_), 512, 0, stream>>>(att, wot, bo, asum);
        k_ln<<<S_, 256, 0, stream>>>(qin + (size_t)b * S_ * D_, asum, gamma, beta,
                                     out + (size_t)b * S_ * D_);
    }
}

// Round 12
// 1044.484 us; speedup vs baseline: 2.7334x; 1.0945x over previous
//
#include <hip/hip_runtime.h>
#include <stdint.h>

#define B_ 4
#define S_ 2048
#define D_ 1024
#define H_ 16
#define A_ 64
#define LN_EPS 1e-3f
#define L2E 1.4426950408889634f

typedef __bf16 bf16x8 __attribute__((ext_vector_type(8)));
typedef __bf16 bf16x4 __attribute__((ext_vector_type(4)));
typedef float f32x4 __attribute__((ext_vector_type(4)));

__device__ __forceinline__ f32x4 mfma16(bf16x8 a, bf16x8 b, f32x4 c) {
    return __builtin_amdgcn_mfma_f32_16x16x32_bf16(a, b, c, 0, 0, 0);
}
__device__ __forceinline__ void glds16(const void* g, void* l) {
    __builtin_amdgcn_global_load_lds(
        (const __attribute__((address_space(1))) void*)g,
        (__attribute__((address_space(3))) void*)l, 16, 0, 0);
}

// ---- swizzled [128][64] half-tile staging ----
#define SWZ(slot, r) ((slot) ^ (((r) & 1) << 2) ^ (((r) >> 1) & 3))
__device__ __forceinline__ void stage_half(const __bf16* __restrict__ src, size_t ld,
                                           __bf16* lhalf, int w, int lane) {
    #pragma unroll
    for (int i = 0; i < 2; ++i) {
        int ch = w * 2 + i;
        int r = ch * 8 + (lane >> 3);
        int sl = SWZ(lane & 7, r);
        glds16(src + (size_t)r * ld + sl * 8, lhalf + ch * 512);
    }
}
__device__ __forceinline__ bf16x8 fragS(const __bf16* h, int r, int ks, int fg) {
    return *(const bf16x8*)(h + r * 64 + SWZ(ks * 4 + fg, r) * 8);
}

// ---- linear [128][32] tile staging (proj 2-phase core), 4 waves ----
__device__ __forceinline__ void glds_tile128(const __bf16* __restrict__ src, size_t ld,
                                             __bf16* lds, int w, int lane) {
    int r = lane >> 2;
    int c = (lane & 3) * 8;
    #pragma unroll
    for (int i = 0; i < 2; ++i) {
        int r0 = (w + i * 4) * 16;
        glds16(src + (size_t)(r0 + r) * ld + c, lds + r0 * 32);
    }
}
template <int NI, int NJ>
__device__ __forceinline__ void mfma_tileL(const __bf16* As, const __bf16* Bs,
                                           int wm, int wn, int fr, int fg,
                                           f32x4 (&acc)[NI][NJ]) {
    bf16x8 af[NI], bv[NJ];
    #pragma unroll
    for (int i = 0; i < NI; ++i)
        af[i] = *(const bf16x8*)(As + (wm + i * 16 + fr) * 32 + fg * 8);
    #pragma unroll
    for (int j = 0; j < NJ; ++j)
        bv[j] = *(const bf16x8*)(Bs + (wn + j * 16 + fr) * 32 + fg * 8);
    #pragma unroll
    for (int i = 0; i < NI; ++i)
        #pragma unroll
        for (int j = 0; j < NJ; ++j)
            acc[i][j] = mfma16(af[i], bv[j], acc[i][j]);
}

// ---------------- tiled transpose + f32->bf16 convert ----------------
__global__ void k_tr_cvt(const float* __restrict__ in, __bf16* __restrict__ out,
                         int R, int C) {
    __shared__ float tile[32][33];
    size_t gbase = (size_t)blockIdx.z * R * C;
    int r0 = blockIdx.y * 32, c0 = blockIdx.x * 32;
    #pragma unroll
    for (int i = threadIdx.y; i < 32; i += 8)
        tile[i][threadIdx.x] = in[gbase + (size_t)(r0 + i) * C + c0 + threadIdx.x];
    __syncthreads();
    #pragma unroll
    for (int i = threadIdx.y; i < 32; i += 8)
        out[gbase + (size_t)(c0 + i) * R + r0 + threadIdx.x] = (__bf16)tile[threadIdx.x][i];
}
__global__ void k_tr_cvt2(const float* __restrict__ in0, const float* __restrict__ in1,
                          __bf16* __restrict__ out0, __bf16* __restrict__ out1,
                          int R, int C) {
    __shared__ float tile[32][33];
    int z = blockIdx.z;
    const float* in = (z < H_) ? in0 : in1;
    __bf16* out = (z < H_) ? out0 : out1;
    size_t gbase = (size_t)(z & (H_ - 1)) * R * C;
    int r0 = blockIdx.y * 32, c0 = blockIdx.x * 32;
    #pragma unroll
    for (int i = threadIdx.y; i < 32; i += 8)
        tile[i][threadIdx.x] = in[gbase + (size_t)(r0 + i) * C + c0 + threadIdx.x];
    __syncthreads();
    #pragma unroll
    for (int i = threadIdx.y; i < 32; i += 8)
        out[gbase + (size_t)(c0 + i) * R + r0 + threadIdx.x] = (__bf16)tile[threadIdx.x][i];
}

// ---------------- elementwise f32 -> bf16 (two sources via z) ----------------
__global__ void k_cvt2(const float* __restrict__ in0, const float* __restrict__ in1,
                       __bf16* __restrict__ out0, __bf16* __restrict__ out1, int n8) {
    int i = blockIdx.x * blockDim.x + threadIdx.x;
    if (i >= n8) return;
    const float* in = blockIdx.y ? in1 : in0;
    __bf16* out = blockIdx.y ? out1 : out0;
    const float4* p = (const float4*)(in + (size_t)i * 8);
    float4 f0 = p[0], f1 = p[1];
    __bf16 v[8] = {(__bf16)f0.x, (__bf16)f0.y, (__bf16)f0.z, (__bf16)f0.w,
                   (__bf16)f1.x, (__bf16)f1.y, (__bf16)f1.z, (__bf16)f1.w};
    *(uint4*)(out + (size_t)i * 8) = *(const uint4*)v;
}

// ---------------- Q/K projection: bf16 glds 2-phase dbuf, both in one dispatch ----------------
__global__ __launch_bounds__(256) void k_proj(
    const __bf16* __restrict__ qb, const __bf16* __restrict__ kvb,
    const __bf16* __restrict__ wqt, const __bf16* __restrict__ wkt,
    const float* __restrict__ bq, const float* __restrict__ bk,
    __bf16* __restrict__ qp, __bf16* __restrict__ kp) {
    __shared__ __bf16 As[2][128 * 32];
    __shared__ __bf16 Bs[2][128 * 32];
    int which = blockIdx.z;
    const __bf16* Ab = which ? kvb : qb;
    const __bf16* Bt = which ? wkt : wqt;
    const float* bias = which ? bk : bq;
    float scale = which ? 1.0f : 0.125f;
    __bf16* outp = which ? kp : qp;
    int m0 = blockIdx.y * 128, n0 = blockIdx.x * 128;
    int t = threadIdx.x, lane = t & 63, w = t >> 6;
    int wm = (w >> 1) * 64, wn = (w & 1) * 64;
    int fr = lane & 15, fg = lane >> 4;
    const __bf16* Abase = Ab + (size_t)m0 * D_;
    const __bf16* Bbase = Bt + (size_t)n0 * D_;
    f32x4 acc[4][4] = {};
    glds_tile128(Abase, D_, As[0], w, lane);
    glds_tile128(Bbase, D_, Bs[0], w, lane);
    __syncthreads();
    int cur = 0;
    const int nt = D_ / 32;
    for (int tt = 0; tt < nt; ++tt) {
        if (tt + 1 < nt) {
            glds_tile128(Abase + (tt + 1) * 32, D_, As[cur ^ 1], w, lane);
            glds_tile128(Bbase + (tt + 1) * 32, D_, Bs[cur ^ 1], w, lane);
        }
        mfma_tileL<4, 4>(As[cur], Bs[cur], wm, wn, fr, fg, acc);
        __syncthreads();
        cur ^= 1;
    }
    #pragma unroll
    for (int j = 0; j < 4; ++j) {
        int n = n0 + wn + j * 16 + fr;
        float bv = bias[n];
        #pragma unroll
        for (int i = 0; i < 4; ++i)
            #pragma unroll
            for (int jj = 0; jj < 4; ++jj) {
                int m = m0 + wm + i * 16 + fg * 4 + jj;
                outp[(size_t)m * (H_ * A_) + n] = (__bf16)((acc[i][j][jj] + bv) * scale);
            }
    }
}

// ---------------- fused flash attention, BN=512, XCD-local, full-tile V cover ----------------
// 1D grid, XCD-aware decode: each XCD owns one n0-half x 4 heads x all yp
// (V panel 2MB + Q/K 1MB ~ L2-resident per XCD).
// V(t+1) issued AFTER the phase-A barrier: provably safe (the barrier's preceding
// lgkmcnt(0) guarantees every wave's PV(t-1) reads of Vs[cur^1] completed), and
// cover = exp + PV + next QK (full K-tile) instead of PV only.
// Ledger: A(t) entry [V(t)x8, kreg(t+1)] -> vmcnt(1) drains V(t); post-barrier
// issue V(t+1) -> [kreg(t+1), V(t+1)x8]; B(t) vmcnt(8) drains kreg(t+1).
__global__ __launch_bounds__(512, 1) void k_fattn(
    const __bf16* __restrict__ qpb, const __bf16* __restrict__ kpb,
    const __bf16* __restrict__ kvtb, __bf16* __restrict__ att) {
    __shared__ __bf16 Ks[64 * 64];          // 8 KB, single buffer
    __shared__ __bf16 Vs[2][4][128 * 64];   // 128 KB
    __shared__ __bf16 Ps[128 * 64];         // 16 KB (also Q staging)
    __shared__ float lpar[128][2];          // 1 KB
    int bid = blockIdx.x;                   // 256 blocks
    int xcd = bid & 7, slot = bid >> 3;     // slot 0..31
    int n0 = (xcd & 1) * 512;
    int h = (xcd >> 1) * 4 + (slot >> 3);
    int yp = slot & 7;
    int t = threadIdx.x, lane = t & 63, w = t >> 6;
    int fr = lane & 15, fg = lane >> 4;
    int wr = w >> 2, wc = w & 3;   // PV: rows wr*64, cols wc*128
    int sr = w >> 1, sc = w & 1;   // QK^T: rows sr*32, cols sc*32
    const __bf16* Vb = kvtb + (size_t)n0 * S_;
    __bf16* ob = att + (size_t)h * S_ * D_;
    int kr = w * 8 + (lane >> 3);       // K stage row (64 rows over 8 waves)
    int ksl = SWZ(lane & 7, kr);        // K stage source slot

    #pragma unroll 1
    for (int seg = 0; seg < 2; ++seg) {
        int mt = seg ? (15 - yp) : yp;
        int m0 = mt * 128;
        int NT = (mt + 1) * 2;
        // ---- prologue: Q -> Ps -> regs; K0 glds; V0 glds; K1 -> reg ----
        stage_half(qpb + (size_t)m0 * (H_ * A_) + h * A_, H_ * A_, Ps, w, lane);
        glds16(kpb + (size_t)kr * (H_ * A_) + h * A_ + ksl * 8, Ks + w * 512);
        asm volatile("s_waitcnt vmcnt(0)" ::: "memory");
        __builtin_amdgcn_s_barrier();
        bf16x8 qf[2][2];
        #pragma unroll
        for (int mi = 0; mi < 2; ++mi)
            #pragma unroll
            for (int ks = 0; ks < 2; ++ks)
                qf[mi][ks] = fragS(Ps, sr * 32 + mi * 16 + fr, ks, fg);
        asm volatile("s_waitcnt lgkmcnt(0)" ::: "memory");
        #pragma unroll
        for (int q = 0; q < 4; ++q)
            stage_half(Vb + (size_t)(q * 128) * S_, S_, &Vs[0][q][0], w, lane);
        uint4 kreg = {0, 0, 0, 0};
        if (NT > 1)
            kreg = *(const uint4*)(kpb + (size_t)(64 + kr) * (H_ * A_) + h * A_ + ksl * 8);
        __builtin_amdgcn_s_barrier();  // Q reads done before P~ writes
        __builtin_amdgcn_sched_barrier(0);
        f32x4 acc[4][8] = {};
        float lsum[2][4] = {};
        int cur = 0;
        for (int tt = 0; tt < NT; ++tt) {
            bool pre = (tt + 1 < NT);
            // ---- phase A: wait V(t); issue V(t+1) post-barrier; QK^T + exp + P~ ----
            if (pre) {
                asm volatile("s_waitcnt vmcnt(1)" ::: "memory");   // drain V(t)x8
            } else {
                asm volatile("s_waitcnt vmcnt(0)" ::: "memory");
            }
            asm volatile("s_waitcnt lgkmcnt(0)" ::: "memory");
            __builtin_amdgcn_s_barrier();
            __builtin_amdgcn_sched_barrier(0);
            if (pre) {
                #pragma unroll
                for (int q = 0; q < 4; ++q)
                    stage_half(Vb + (size_t)(q * 128) * S_ + (tt + 1) * 64, S_,
                               &Vs[cur ^ 1][q][0], w, lane);
            }
            f32x4 sac[2][2] = {};
            __builtin_amdgcn_s_setprio(1);
            #pragma unroll
            for (int ks = 0; ks < 2; ++ks)
                #pragma unroll
                for (int nj = 0; nj < 2; ++nj) {
                    bf16x8 kf = fragS(Ks, sc * 32 + nj * 16 + fr, ks, fg);
                    #pragma unroll
                    for (int mi = 0; mi < 2; ++mi)
                        sac[mi][nj] = mfma16(qf[mi][ks], kf, sac[mi][nj]);
                }
            __builtin_amdgcn_s_setprio(0);
            bool dg = (tt >= 2 * mt);   // block-uniform: only last 2 tiles touch diagonal
            if (dg) {
                #pragma unroll
                for (int mi = 0; mi < 2; ++mi)
                    #pragma unroll
                    for (int nj = 0; nj < 2; ++nj)
                        #pragma unroll
                        for (int jj = 0; jj < 4; ++jj) {
                            int srow = sr * 32 + mi * 16 + fg * 4 + jj;
                            int col = sc * 32 + nj * 16 + fr;
                            float p = exp2f(sac[mi][nj][jj] * L2E);
                            if (tt * 64 + col > m0 + srow) p = 0.f;
                            lsum[mi][jj] += p;
                            Ps[srow * 64 + (col ^ (fg << 4))] = (__bf16)p;
                        }
            } else {
                #pragma unroll
                for (int mi = 0; mi < 2; ++mi)
                    #pragma unroll
                    for (int nj = 0; nj < 2; ++nj)
                        #pragma unroll
                        for (int jj = 0; jj < 4; ++jj) {
                            int srow = sr * 32 + mi * 16 + fg * 4 + jj;
                            int col = sc * 32 + nj * 16 + fr;
                            float p = exp2f(sac[mi][nj][jj] * L2E);
                            lsum[mi][jj] += p;
                            Ps[srow * 64 + (col ^ (fg << 4))] = (__bf16)p;
                        }
            }
            asm volatile("s_waitcnt lgkmcnt(0)" ::: "memory");
            __builtin_amdgcn_s_barrier();
            __builtin_amdgcn_sched_barrier(0);
            // ---- phase B: K(t+1) reg->LDS; PV ----
            if (pre) {
                asm volatile("s_waitcnt vmcnt(8)" ::: "memory");   // drain kreg(t+1)
                *(uint4*)(Ks + w * 512 + lane * 8) = kreg;
                if (tt + 2 < NT)
                    kreg = *(const uint4*)(kpb + (size_t)((tt + 2) * 64 + kr) * (H_ * A_) +
                                           h * A_ + ksl * 8);
            }
            __builtin_amdgcn_s_setprio(1);
            const __bf16* Vh = &Vs[cur][wc][0];
            #pragma unroll
            for (int ks = 0; ks < 2; ++ks) {
                bf16x8 pa[4], vf[8];
                #pragma unroll
                for (int mi = 0; mi < 4; ++mi) {
                    int r = wr * 64 + mi * 16 + fr;
                    int g = (ks * 4 + fg) ^ (((fr >> 2) & 3) << 1);
                    pa[mi] = *(const bf16x8*)(Ps + r * 64 + g * 8);
                }
                #pragma unroll
                for (int nj = 0; nj < 8; ++nj)
                    vf[nj] = fragS(Vh, nj * 16 + fr, ks, fg);
                #pragma unroll
                for (int mi = 0; mi < 4; ++mi)
                    #pragma unroll
                    for (int nj = 0; nj < 8; ++nj)
                        acc[mi][nj] = mfma16(pa[mi], vf[nj], acc[mi][nj]);
            }
            __builtin_amdgcn_s_setprio(0);
            __builtin_amdgcn_sched_barrier(0);
            cur ^= 1;
        }
        // ---- row sums: shfl over fr, combine the 2 col-waves via LDS ----
        #pragma unroll
        for (int mi = 0; mi < 2; ++mi)
            #pragma unroll
            for (int jj = 0; jj < 4; ++jj) {
                float v = lsum[mi][jj];
                v += __shfl_xor(v, 1);
                v += __shfl_xor(v, 2);
                v += __shfl_xor(v, 4);
                v += __shfl_xor(v, 8);
                if (fr == 0) lpar[sr * 32 + mi * 16 + fg * 4 + jj][sc] = v;
            }
        asm volatile("s_waitcnt lgkmcnt(0)" ::: "memory");
        __builtin_amdgcn_s_barrier();
        // ---- epilogue: normalize + store ----
        #pragma unroll
        for (int mi = 0; mi < 4; ++mi)
            #pragma unroll
            for (int jj = 0; jj < 4; ++jj) {
                int row = wr * 64 + mi * 16 + fg * 4 + jj;
                float il = 1.f / (lpar[row][0] + lpar[row][1]);
                int m = m0 + row;
                #pragma unroll
                for (int nj = 0; nj < 8; ++nj) {
                    int n = n0 + wc * 128 + nj * 16 + fr;
                    ob[(size_t)m * D_ + n] = (__bf16)(acc[mi][nj][jj] * il);
                }
            }
        __builtin_amdgcn_s_barrier();  // Ps/lpar/Ks reuse across segs
    }
}

// ---------------- per-head Wo GEMM + bias + relu -> bf16 partials, 256^2 8-phase ----------------
// 1D grid, XCD-aware decode: each XCD owns a head-pair (wot panel L2-resident).
__global__ __launch_bounds__(512) void k_headsum(
    const __bf16* __restrict__ att, const __bf16* __restrict__ Wot,
    const float* __restrict__ bo, __bf16* __restrict__ asum) {
    __shared__ __bf16 L[2][4][8192];
    int bid = blockIdx.x;                    // 512 blocks
    int xcd = bid & 7, slot = bid >> 3;      // slot 0..63
    int p = xcd * 2 + (slot >> 5);           // head 0..15
    int rem = slot & 31;
    int mt = rem >> 2;                       // 0..7
    int n0 = (rem & 3) * 256;
    int m0 = mt * 256;
    int t = threadIdx.x, lane = t & 63, w = t >> 6;
    int wr = w >> 2, wc = w & 3;
    int fr = lane & 15, fg = lane >> 4;
    const __bf16* Ab = att + ((size_t)p * S_ + m0) * D_;
    const __bf16* Bb = Wot + ((size_t)p * D_ + n0) * D_;
    float bv4[4];
    #pragma unroll
    for (int j = 0; j < 4; ++j)
        bv4[j] = bo[(size_t)p * D_ + n0 + wc * 64 + j * 16 + fr];
    f32x4 acc[8][4] = {};
    auto stg = [&](int tt, int h, int buf) {
        const __bf16* s = (h < 2) ? (Ab + (size_t)(h * 128) * D_ + tt * 64)
                                  : (Bb + (size_t)((h - 2) * 128) * D_ + tt * 64);
        stage_half(s, D_, &L[buf][h][0], w, lane);
    };
    auto loads = [&](const __bf16* Ah, const __bf16* Bh, int rb0, int mh, int nh,
                     bf16x8 (&af)[4][2], bf16x8 (&bv)[2][2]) {
        #pragma unroll
        for (int i = 0; i < 4; ++i)
            #pragma unroll
            for (int ks = 0; ks < 2; ++ks)
                af[i][ks] = fragS(Ah, mh * 64 + i * 16 + fr, ks, fg);
        #pragma unroll
        for (int j = 0; j < 2; ++j)
            #pragma unroll
            for (int ks = 0; ks < 2; ++ks)
                bv[j][ks] = fragS(Bh, rb0 + nh * 32 + j * 16 + fr, ks, fg);
    };
    stg(0, 0, 0); stg(0, 1, 0); stg(0, 2, 0); stg(0, 3, 0);
    int cur = 0;
    const int nt = D_ / 64;
    for (int tt = 0; tt < nt; ++tt) {
        bool pre = (tt + 1 < nt);
        const __bf16* Ah = &L[cur][wr][0];
        const __bf16* Bh = &L[cur][2 + (wc >> 1)][0];
        int rb0 = (wc & 1) * 64;
        #pragma unroll
        for (int ph = 0; ph < 4; ++ph) {
            const int mh = ph >> 1, nh = ph & 1;
            bf16x8 af[4][2], bv[2][2];
            if (ph == 0) {
                if (pre) {
                    stg(tt + 1, 0, cur ^ 1);
                    stg(tt + 1, 1, cur ^ 1);
                    stg(tt + 1, 2, cur ^ 1);
                    stg(tt + 1, 3, cur ^ 1);
                    asm volatile("s_waitcnt vmcnt(8)" ::: "memory");
                } else {
                    asm volatile("s_waitcnt vmcnt(0)" ::: "memory");
                }
                __builtin_amdgcn_s_barrier();
                __builtin_amdgcn_sched_barrier(0);
                loads(Ah, Bh, rb0, mh, nh, af, bv);
            } else {
                loads(Ah, Bh, rb0, mh, nh, af, bv);
                __builtin_amdgcn_s_barrier();
                __builtin_amdgcn_sched_barrier(0);
            }
            __builtin_amdgcn_s_setprio(1);
            #pragma unroll
            for (int i = 0; i < 4; ++i)
                #pragma unroll
                for (int j = 0; j < 2; ++j) {
                    acc[mh * 4 + i][nh * 2 + j] =
                        mfma16(af[i][0], bv[j][0], acc[mh * 4 + i][nh * 2 + j]);
                    acc[mh * 4 + i][nh * 2 + j] =
                        mfma16(af[i][1], bv[j][1], acc[mh * 4 + i][nh * 2 + j]);
                }
            __builtin_amdgcn_s_setprio(0);
            __builtin_amdgcn_sched_barrier(0);
            __builtin_amdgcn_s_barrier();
        }
        cur ^= 1;
    }
    __bf16* dst = asum + ((size_t)p * S_ + m0) * D_;
    #pragma unroll
    for (int mi = 0; mi < 8; ++mi)
        #pragma unroll
        for (int jj = 0; jj < 4; ++jj) {
            int mr = wr * 128 + mi * 16 + fg * 4 + jj;
            #pragma unroll
            for (int nj = 0; nj < 4; ++nj) {
                int nc = n0 + wc * 64 + nj * 16 + fr;
                dst[(size_t)mr * D_ + nc] = (__bf16)fmaxf(acc[mi][nj][jj] + bv4[nj], 0.f);
            }
        }
}

// ---------------- residual + 16-partial bf16 sum + LayerNorm (per batch) ----------------
__global__ __launch_bounds__(256) void k_ln(
    const float* __restrict__ x1b, const __bf16* __restrict__ parts,
    const float* __restrict__ gamma, const float* __restrict__ beta,
    float* __restrict__ outb) {
    int row = blockIdx.x;
    size_t base = (size_t)row * D_;
    int c = threadIdx.x * 4;
    float4 a = *(const float4*)(x1b + base + c);
    float x[4] = {a.x, a.y, a.z, a.w};
    #pragma unroll
    for (int p = 0; p < H_; ++p) {
        bf16x4 v = *(const bf16x4*)(parts + ((size_t)p * S_ + row) * D_ + c);
        x[0] += (float)v[0]; x[1] += (float)v[1];
        x[2] += (float)v[2]; x[3] += (float)v[3];
    }
    float sm = x[0] + x[1] + x[2] + x[3];
    float s2 = x[0] * x[0] + x[1] * x[1] + x[2] * x[2] + x[3] * x[3];
    #pragma unroll
    for (int m = 32; m >= 1; m >>= 1) {
        sm += __shfl_xor(sm, m);
        s2 += __shfl_xor(s2, m);
    }
    __shared__ float r1[4], r2[4];
    int w = threadIdx.x >> 6;
    if ((threadIdx.x & 63) == 0) { r1[w] = sm; r2[w] = s2; }
    __syncthreads();
    sm = r1[0] + r1[1] + r1[2] + r1[3];
    s2 = r2[0] + r2[1] + r2[2] + r2[3];
    float mean = sm * (1.f / D_);
    float var = s2 * (1.f / D_) - mean * mean;
    float rstd = rsqrtf(var + LN_EPS);
    #pragma unroll
    for (int jj = 0; jj < 4; ++jj)
        outb[base + c + jj] = gamma[c + jj] * (x[jj] - mean) * rstd + beta[c + jj];
}

// ---------------- host ----------------
extern "C" void kernel_launch(void* const* d_in, const int* in_sizes, int n_in,
                              void* d_out, int out_size, void* d_ws, size_t ws_size,
                              hipStream_t stream) {
    (void)in_sizes; (void)n_in; (void)out_size; (void)ws_size;
    const float* qin   = (const float*)d_in[0];
    const float* kvin  = (const float*)d_in[1];
    const float* Wq    = (const float*)d_in[2];
    const float* bq    = (const float*)d_in[3];
    const float* Wk    = (const float*)d_in[4];
    const float* bk    = (const float*)d_in[5];
    const float* Wo    = (const float*)d_in[6];
    const float* bo    = (const float*)d_in[7];
    const float* gamma = (const float*)d_in[8];
    const float* beta  = (const float*)d_in[9];
    float* out = (float*)d_out;
    char* ws = (char*)d_ws;

    size_t off = 0;
    auto alloc = [&](size_t bytes) {
        size_t o = off;
        off += (bytes + 255) & ~(size_t)255;
        return o;
    };
    size_t o_wqt = alloc((size_t)H_ * A_ * D_ * 2);
    size_t o_wkt = alloc((size_t)H_ * A_ * D_ * 2);
    size_t o_wot = alloc((size_t)H_ * D_ * D_ * 2);
    size_t o_kvt = alloc((size_t)B_ * D_ * S_ * 2);
    size_t o_qp  = alloc((size_t)B_ * S_ * H_ * A_ * 2);
    size_t o_kp  = alloc((size_t)B_ * S_ * H_ * A_ * 2);
    size_t o_att = alloc((size_t)H_ * S_ * D_ * 2);
    // region X: qb+kvb (proj inputs) then asum (bf16 partials) — disjoint lifetimes
    size_t xbytes_qb = (size_t)B_ * S_ * D_ * 2 * 2;
    size_t xbytes_as = (size_t)H_ * S_ * D_ * 2;
    size_t o_x = alloc(xbytes_qb > xbytes_as ? xbytes_qb : xbytes_as);

    __bf16* wqt = (__bf16*)(ws + o_wqt);
    __bf16* wkt = (__bf16*)(ws + o_wkt);
    __bf16* wot = (__bf16*)(ws + o_wot);
    __bf16* kvt = (__bf16*)(ws + o_kvt);
    __bf16* qp  = (__bf16*)(ws + o_qp);
    __bf16* kp  = (__bf16*)(ws + o_kp);
    __bf16* att = (__bf16*)(ws + o_att);
    __bf16* qb  = (__bf16*)(ws + o_x);
    __bf16* kvb = qb + (size_t)B_ * S_ * D_;
    __bf16* asum = (__bf16*)(ws + o_x);

    k_tr_cvt2<<<dim3(A_ / 32, D_ / 32, 2 * H_), dim3(32, 8), 0, stream>>>(
        Wq, Wk, wqt, wkt, D_, A_);
    k_tr_cvt<<<dim3(D_ / 32, D_ / 32, H_), dim3(32, 8), 0, stream>>>(Wo, wot, D_, D_);
    k_tr_cvt<<<dim3(D_ / 32, S_ / 32, B_), dim3(32, 8), 0, stream>>>(kvin, kvt, S_, D_);
    int n8 = B_ * S_ * D_ / 8;
    k_cvt2<<<dim3((n8 + 255) / 256, 2), 256, 0, stream>>>(qin, kvin, qb, kvb, n8);
    k_proj<<<dim3(8, 64, 2), 256, 0, stream>>>(qb, kvb, wqt, wkt, bq, bk, qp, kp);

    for (int b = 0; b < B_; ++b) {
        const __bf16* qpb  = qp + (size_t)b * S_ * (H_ * A_);
        const __bf16* kpb  = kp + (size_t)b * S_ * (H_ * A_);
        const __bf16* kvtb = kvt + (size_t)b * D_ * S_;
        k_fattn<<<256, 512, 0, stream>>>(qpb, kpb, kvtb, att);
        k_headsum<<<512, 512, 0, stream>>>(att, wot, bo, asum);
        k_ln<<<S_, 256, 0, stream>>>(qin + (size_t)b * S_ * D_, asum, gamma, beta,
                                     out + (size_t)b * S_ * D_);
    }
}